// Round 2
// baseline (15518.677 us; speedup 1.0000x reference)
//
#include <hip/hip_runtime.h>
#include <cstdint>
#include <cstddef>

// ---------------------------------------------------------------------------
// PurifiedVAE persistent-RNN, round 8.
// enc: persist_kernel<0>, 256 WGs = 4 chains (2 dir x 2 batch-halves) x 64 WGs.
// dec: persist_kernel<1>, 128 producer WGs (2 chains x 64) + 8 out-head WGs.
// Weights LDS-resident all 512 steps; fp32 h master in registers.
// r8 CHANGE: A-gather is now L1/L2-CACHED (plain global_load_dwordx4, no
// sc0/sc1) + a per-step agent-scope ACQUIRE fence (compiler emits the L1+L2
// invalidate required on multi-XCD gfx950) issued after the flag spin and
// before the gather. The 8 WGs of a chain resident on one XCD now share the
// 256 KB h-panel through that XCD's L2 instead of each pulling it from the
// Infinity Cache: per-step LLC read traffic drops ~8x (64 MB -> ~8 MB fills).
// Producer h16 stores stay write-through sc0|sc1 (LLC visibility proven by
// the vmcnt-drain + flag protocol of earlier rounds) -- correctness of the
// cached reads rests on the acquire fence, not on WG->XCD placement.
// Sync: unchanged (per-WG one-shot flag slots, value = step+1, wave polling).
// ---------------------------------------------------------------------------

typedef _Float16 f16;
typedef _Float16 f16x8 __attribute__((ext_vector_type(8)));
typedef float f32x4 __attribute__((ext_vector_type(4)));

#define NB 256
#define NT 512
#define NI 12
#define NH 1024
#define NZ 128
#define NG 3072
#define KE_ENC 1056   // 1024 + 32 ext (x,1,pad)
#define KE_DEC 1184   // 1024 + 160 ext (x,1,pad,z128)
#define XK_ENC 32
#define XK_DEC 160
#define ZXP 40        // Zx row stride in halves (pad: 80 B rows, 2-way banks)

#define MFMA16(a, b, c) __builtin_amdgcn_mfma_f32_16x16x32_f16((a), (b), (c), 0, 0, 0)

// ---- workspace layout (bytes) ----
#define OFF_WMF   ((size_t)0)
#define OFF_WMB   (OFF_WMF + (size_t)NG * KE_ENC * 2)
#define OFF_WMD   (OFF_WMB + (size_t)NG * KE_ENC * 2)
#define OFF_WNF   (OFF_WMD + (size_t)NG * KE_DEC * 2)
#define OFF_WNB   (OFF_WNF + (size_t)NH * XK_ENC * 2)
#define OFF_WND   (OFF_WNB + (size_t)NH * XK_ENC * 2)
#define OFF_WOUT  (OFF_WND + (size_t)NH * XK_DEC * 2)
#define OFF_HENC16 (OFF_WOUT + (size_t)16 * KE_ENC * 2)   // [2 dir][2 buf][NB*NH] f16
#define OFF_HF32   (OFF_HENC16 + (size_t)4 * NB * NH * 2) // [2 dir][NB*NH] f32
#define OFF_HDEC16 (OFF_HF32 + (size_t)2 * NB * NH * 4)   // [2 buf][NB*NH] f16
#define OFF_H32D   (OFF_HDEC16 + (size_t)2 * NB * NH * 2) // [NB*NH] f32
#define OFF_Z32    (OFF_H32D + (size_t)NB * NH * 4)
#define OFF_Z16    (OFF_Z32 + (size_t)NB * NZ * 4)
#define OFF_FLG    (OFF_Z16 + (size_t)NB * NZ * 2)
// flags: enc 4*512*64 | dec 2*512*64 | out 2*512*8  = 204800 u32
#define N_FLG 204800
#define WS_NEEDED (OFF_FLG + (size_t)N_FLG * 4)

// d_out element offsets (fp32): recon [256,512,12], mean [256,128], stddev [256,128]
#define OUT_MEAN (NB * NT * NI)
#define OUT_STD  (OUT_MEAN + NB * NZ)

// whole-wave flag poll: lanes watch nslots (power of 2) slots in parallel.
__device__ __forceinline__ void wave_spin(const unsigned* base, unsigned tgt,
                                          int lane, int nslots) {
    const unsigned* p = base + (lane & (nslots - 1));
    for (;;) {
        unsigned v = __hip_atomic_load(p, __ATOMIC_RELAXED, __HIP_MEMORY_SCOPE_AGENT);
        if (__all((int)(v == tgt))) break;
        __builtin_amdgcn_s_sleep(1);
    }
}

// agent-scope acquire: invalidates L1+L2 so cached gathers of the ping-pong
// h buffers cannot observe stale lines from 2 steps ago (cross-XCD safety).
#define ACQ() __builtin_amdgcn_fence(__ATOMIC_ACQUIRE, "agent")

// counted vmcnt wait + scheduling fence. Mask 0x387 = ALU|VALU|SALU|DS|
// DS_READ|DS_WRITE may cross; MFMA (0x8) and VMEM (0x70) may NOT -- this is
// the rule-18 fence keeping register-only MFMAs below the waitcnt while still
// letting the compiler prefetch B-fragment ds_reads across chunk boundaries.
#define PW(N) do { \
    asm volatile("s_waitcnt vmcnt(%0)" :: "n"(N) : "memory"); \
    __builtin_amdgcn_sched_barrier(0x387); \
} while (0)

// ---------------------------------------------------------------------------
// prep: build fp16 extended weight matrices, zero initial enc h16 buffers,
// zero flag arrays. (extended-K layout: see earlier rounds; unchanged)
// ---------------------------------------------------------------------------
__global__ __launch_bounds__(256) void prep_kernel(
    const float* __restrict__ Whhf, const float* __restrict__ Wihf,
    const float* __restrict__ bihf, const float* __restrict__ bhhf,
    const float* __restrict__ Whhb, const float* __restrict__ Wihb,
    const float* __restrict__ bihb, const float* __restrict__ bhhb,
    const float* __restrict__ Wchh, const float* __restrict__ Wcih,
    const float* __restrict__ bcih, const float* __restrict__ bchh,
    const float* __restrict__ Wo,   const float* __restrict__ bo,
    f16* __restrict__ wmf, f16* __restrict__ wmb, f16* __restrict__ wmd,
    f16* __restrict__ wnf, f16* __restrict__ wnb, f16* __restrict__ wnd,
    f16* __restrict__ wout,
    f16* __restrict__ h16e0f, f16* __restrict__ h16e0b,
    unsigned* __restrict__ flgs)
{
    const int gsz = gridDim.x * blockDim.x;
    const int gid = blockIdx.x * blockDim.x + threadIdx.x;

    for (int idx = gid; idx < NG * KE_ENC; idx += gsz) {
        const int c = idx / KE_ENC, k = idx - c * KE_ENC;
        float vf, vb;
        if (k < NH) { vf = Whhf[c * NH + k]; vb = Whhb[c * NH + k]; }
        else {
            const int e = k - NH;
            if (c < 2 * NH) {
                if (e < 12)       { vf = Wihf[c * 12 + e]; vb = Wihb[c * 12 + e]; }
                else if (e == 12) { vf = bihf[c] + bhhf[c]; vb = bihb[c] + bhhb[c]; }
                else              { vf = 0.f; vb = 0.f; }
            } else {
                vf = (e == 12) ? bhhf[c] : 0.f;
                vb = (e == 12) ? bhhb[c] : 0.f;
            }
        }
        wmf[idx] = (f16)vf; wmb[idx] = (f16)vb;
    }
    for (int idx = gid; idx < NG * KE_DEC; idx += gsz) {
        const int c = idx / KE_DEC, k = idx - c * KE_DEC;
        float v;
        if (k < NH) v = Wchh[c * NH + k];
        else {
            const int e = k - NH;
            if (c < 2 * NH) {
                if (e < 12)       v = Wcih[c * 140 + e];
                else if (e == 12) v = bcih[c] + bchh[c];
                else if (e < 32)  v = 0.f;
                else              v = Wcih[c * 140 + 12 + (e - 32)];
            } else v = (e == 12) ? bchh[c] : 0.f;
        }
        wmd[idx] = (f16)v;
    }
    for (int idx = gid; idx < NH * XK_ENC; idx += gsz) {
        const int j = idx >> 5, e = idx & 31;
        const int c = 2 * NH + j;
        float vf, vb;
        if (e < 12)       { vf = Wihf[c * 12 + e]; vb = Wihb[c * 12 + e]; }
        else if (e == 12) { vf = bihf[c]; vb = bihb[c]; }
        else              { vf = 0.f; vb = 0.f; }
        wnf[idx] = (f16)vf; wnb[idx] = (f16)vb;
    }
    for (int idx = gid; idx < NH * XK_DEC; idx += gsz) {
        const int j = idx / XK_DEC, e = idx - j * XK_DEC;
        const int c = 2 * NH + j;
        float v;
        if (e < 12)       v = Wcih[c * 140 + e];
        else if (e == 12) v = bcih[c];
        else if (e < 32)  v = 0.f;
        else              v = Wcih[c * 140 + 12 + (e - 32)];
        wnd[idx] = (f16)v;
    }
    for (int idx = gid; idx < 16 * KE_ENC; idx += gsz) {
        const int i = idx / KE_ENC, k = idx - i * KE_ENC;
        float v = 0.f;
        if (i < 12) {
            if (k < NH) v = Wo[i * NH + k];
            else if (k == NH + 12) v = bo[i];
        }
        wout[idx] = (f16)v;
    }
    for (int idx = gid; idx < NB * NH; idx += gsz) {
        h16e0f[idx] = (f16)0.f; h16e0b[idx] = (f16)0.f;
    }
    for (int idx = gid; idx < N_FLG; idx += gsz) flgs[idx] = 0u;
}

// ---------------------------------------------------------------------------
// persist_kernel<MODE>: MODE 0 = encoder (grid 256), MODE 1 = decoder (grid 136).
// Producer WG: chain = bid>>6, slice = bid&63 -> 48 gate-cols {r,z,n} of 16
// h-cols, M=128 batch rows.  Waves M-split 32 rows (2 row-tiles); A fragments
// gathered straight to registers (depth-8 chunk pipeline, no intra-K barriers).
// Out-head WGs (dec, bid>=128): 32 rows x 16 out-cols each, K=1024 wout + ext.
// ---------------------------------------------------------------------------
template<int MODE>
__global__ __launch_bounds__(256, 1) void persist_kernel(
    const float* __restrict__ x,
    const f16* __restrict__ wmF, const f16* __restrict__ wmB_,
    const f16* __restrict__ wnF, const f16* __restrict__ wnB_,
    const f16* __restrict__ wout, const f16* __restrict__ z16,
    f16* __restrict__ hbuf,          // enc: [dir][2][NB*NH]; dec: [2][NB*NH]
    float* __restrict__ hf32,        // enc final fp32 out [dir][NB*NH]
    const float* __restrict__ h32i,  // dec initial master (heads2)
    float* __restrict__ dout,
    unsigned* __restrict__ flg,      // enc [4][512][64] ; dec [2][512][64]
    unsigned* __restrict__ flg_out)  // dec [2][512][8]
{
    constexpr int KE  = MODE ? KE_DEC : KE_ENC;
    constexpr int KEP = KE + 8;
    constexpr int XK  = MODE ? XK_DEC : XK_ENC;
    constexpr int XKP = XK + 8;
    constexpr int NZT = MODE ? 4 : 0;   // z-register A k-tiles

    __shared__ f16 Wlds[48 * KEP];      // enc 99.8 KB / dec 111.8 KB
    __shared__ f16 Zx[128 * ZXP];       // 10 KB per-step x+bias A-ext rows
    __shared__ f16 wnlds[16 * XKP];     // gi_n ext weights

    const int tid = threadIdx.x;
    const int bid = blockIdx.x;
    const int w = tid >> 6, lane = tid & 63;
    const int lr = lane & 15, quad = lane >> 4;

    if (MODE == 1 && bid >= 128) {
        // ---------------- out-head consumer WGs ----------------
        const int oc = bid - 128;                 // 0..7
        const int ochain = oc >> 2;
        const int mbase = ochain * 128 + (oc & 3) * 32;
        for (int u = tid; u < 16 * 132; u += 256) {
            const int r = u / 132, kk = u - r * 132;
            *(uint4*)&Wlds[r * 1064 + kk * 8] =
                *(const uint4*)(wout + (size_t)r * KE_ENC + kk * 8);
        }
        __syncthreads();
        if (w >= 2) return;                       // 2 active waves (16 rows each)
        const int rb = mbase + w * 16;
        f16x8 ax;                                 // A-ext: 1.0 at e==12
#pragma unroll
        for (int j = 0; j < 8; ++j) ax[j] = (f16)0.f;
        if (quad == 1) ax[4] = (f16)1.f;

#define OISSUE(c) do { \
    asm volatile( \
        "global_load_dwordx4 %0, %2, off offset:%3\n\t" \
        "global_load_dwordx4 %1, %2, off offset:%4" \
        : "=&v"(ov[(c) & 7][0]), "=&v"(ov[(c) & 7][1]) \
        : "v"(gao), "n"((c) * 128), "n"((c) * 128 + 64) \
        : "memory"); \
} while (0)
#define OCONS(c) do { \
    _Pragma("unroll") \
    for (int kt2_ = 0; kt2_ < 2; ++kt2_) { \
        const f16x8 b_ = *(const f16x8*)(&Wlds[lr * 1064 + ((c) * 2 + kt2_) * 32 + (quad << 3)]); \
        accq = MFMA16(ov[(c) & 7][kt2_], b_, accq); \
    } \
} while (0)

#pragma unroll 1
        for (int t = 0; t < NT; ++t) {
            wave_spin(flg + ((size_t)ochain * 512 + t) * 64, (unsigned)(t + 1),
                      lane, 64);
            ACQ();   // invalidate L1/L2 before cached gather of ping-pong buf
            const f16* hc = hbuf + (size_t)((t + 1) & 1) * (NB * NH);
            const char* gao = (const char*)(hc + (size_t)(rb + lr) * NH) + (quad << 4);
            f32x4 accq = {0.f, 0.f, 0.f, 0.f};
            f16x8 ov[8][2];
            OISSUE(0); OISSUE(1); OISSUE(2); OISSUE(3);
            OISSUE(4); OISSUE(5); OISSUE(6); OISSUE(7);
            PW(14); OCONS(0);  OISSUE(8);
            PW(14); OCONS(1);  OISSUE(9);
            PW(14); OCONS(2);  OISSUE(10);
            PW(14); OCONS(3);  OISSUE(11);
            PW(14); OCONS(4);  OISSUE(12);
            PW(14); OCONS(5);  OISSUE(13);
            PW(14); OCONS(6);  OISSUE(14);
            PW(14); OCONS(7);  OISSUE(15);
            PW(14); OCONS(8);
            PW(12); OCONS(9);
            PW(10); OCONS(10);
            PW(8);  OCONS(11);
            PW(6);  OCONS(12);
            PW(4);  OCONS(13);
            PW(2);  OCONS(14);
            PW(0);
            // all hbuf reads have landed in registers: release the ping-pong buffer
            if (lane == 0)
                __hip_atomic_store(
                    &flg_out[((size_t)ochain * 512 + t) * 8 + (oc & 3) * 2 + w],
                    (unsigned)(t + 1), __ATOMIC_RELAXED, __HIP_MEMORY_SCOPE_AGENT);
            OCONS(15);
            {
                const f16x8 b = *(const f16x8*)(&Wlds[lr * 1064 + 1024 + (quad << 3)]);
                accq = MFMA16(ax, b, accq);
            }
            if (lr < NI) {
#pragma unroll
                for (int r = 0; r < 4; ++r) {
                    const int b_ = rb + quad * 4 + r;
                    dout[(size_t)b_ * (NT * NI) + t * NI + lr] =
                        1.f / (1.f + __expf(-accq[r]));
                }
            }
        }
#undef OISSUE
#undef OCONS
        return;
    }

    // ---------------- producer WGs ----------------
    const int chain = bid >> 6;                 // enc 0..3, dec 0..1
    const int slice = bid & 63;
    const int dir = MODE ? 0 : (chain >> 1);
    const int m0 = MODE ? chain * 128 : (chain & 1) * 128;
    const int j0 = slice * 16;

    const f16* wm = (MODE == 0 && dir) ? wmB_ : wmF;
    const f16* wn = (MODE == 0 && dir) ? wnB_ : wnF;
    f16* hb0 = hbuf + (MODE ? (size_t)0 : (size_t)dir * 2 * NB * NH);

    // one-time weight load into LDS + Zx zero-init (halves 16..31 stay 0!)
    constexpr int KQ = KE / 8;
    for (int u = tid; u < 48 * KQ; u += 256) {
        const int r = u / KQ, kk = u - r * KQ;
        const int c = (r >> 4) * NH + j0 + (r & 15);
        *(uint4*)&Wlds[r * KEP + kk * 8] = *(const uint4*)(wm + (size_t)c * KE + kk * 8);
    }
    constexpr int XQ = XK / 8;
    for (int u = tid; u < 16 * XQ; u += 256) {
        const int r = u / XQ, kk = u - r * XQ;
        *(uint4*)&wnlds[r * XKP + kk * 8] =
            *(const uint4*)(wn + (size_t)(j0 + r) * XK + kk * 8);
    }
    for (int u = tid; u < 128 * ZXP / 8; u += 256)
        *(uint4*)&Zx[u * 8] = make_uint4(0u, 0u, 0u, 0u);
    __syncthreads();

    // register-resident fp32 h master + constant z A-fragments
    float hmast[2][4];
    f16x8 azr[2][NZT ? NZT : 1];
#pragma unroll
    for (int rt = 0; rt < 2; ++rt)
#pragma unroll
        for (int r = 0; r < 4; ++r)
            hmast[rt][r] = MODE
                ? h32i[(size_t)(m0 + (w << 5) + rt * 16 + quad * 4 + r) * NH + j0 + lr]
                : 0.f;
    if (MODE) {
#pragma unroll
        for (int rt = 0; rt < 2; ++rt)
#pragma unroll
            for (int zt = 0; zt < NZT; ++zt)
                azr[rt][zt] = *(const f16x8*)(z16 +
                    (size_t)(m0 + (w << 5) + rt * 16 + lr) * NZ + zt * 32 + (quad << 3));
    }

    unsigned* myflg = flg + (size_t)chain * 512 * 64;

#define AISSUE(c) do { \
    asm volatile( \
        "global_load_dwordx4 %0, %4, off offset:%6\n\t" \
        "global_load_dwordx4 %1, %5, off offset:%6\n\t" \
        "global_load_dwordx4 %2, %4, off offset:%7\n\t" \
        "global_load_dwordx4 %3, %5, off offset:%7" \
        : "=&v"(av[(c) & 7][0]), "=&v"(av[(c) & 7][1]), \
          "=&v"(av[(c) & 7][2]), "=&v"(av[(c) & 7][3]) \
        : "v"(ga0), "v"(ga1), "n"((c) * 128), "n"((c) * 128 + 64) \
        : "memory"); \
} while (0)
#define PCONS(c) do { \
    _Pragma("unroll") \
    for (int kt2_ = 0; kt2_ < 2; ++kt2_) { \
        const f16x8 a0_ = av[(c) & 7][kt2_ * 2]; \
        const f16x8 a1_ = av[(c) & 7][kt2_ * 2 + 1]; \
        _Pragma("unroll") \
        for (int g_ = 0; g_ < 3; ++g_) { \
            const f16x8 b_ = *(const f16x8*)(&Wlds[(g_ * 16 + lr) * KEP + ((c) * 2 + kt2_) * 32 + (quad << 3)]); \
            acc[g_][0] = MFMA16(a0_, b_, acc[g_][0]); \
            acc[g_][1] = MFMA16(a1_, b_, acc[g_][1]); \
        } \
    } \
} while (0)

#pragma unroll 1
    for (int t = 0; t < NT; ++t) {
        // stage per-step A-ext rows (x teacher / x_t, bias 1 at e==12)
        if (tid < 128) {
            f16 rowv[16];
            if (MODE == 1 && t == 0) {
#pragma unroll
                for (int e = 0; e < 12; ++e) rowv[e] = (f16)((e == NI - 1) ? 1.f : 0.f);
            } else {
                const int b_ = m0 + tid;
                const int tx = MODE ? (t - 1) : (dir ? (NT - 1 - t) : t);
                const float4* xr = (const float4*)(x + ((size_t)b_ * NT + tx) * NI);
                const float4 x0 = xr[0], x1 = xr[1], x2 = xr[2];
                rowv[0] = (f16)x0.x; rowv[1] = (f16)x0.y; rowv[2] = (f16)x0.z; rowv[3] = (f16)x0.w;
                rowv[4] = (f16)x1.x; rowv[5] = (f16)x1.y; rowv[6] = (f16)x1.z; rowv[7] = (f16)x1.w;
                rowv[8] = (f16)x2.x; rowv[9] = (f16)x2.y; rowv[10] = (f16)x2.z; rowv[11] = (f16)x2.w;
            }
            rowv[12] = (f16)1.f; rowv[13] = (f16)0.f; rowv[14] = (f16)0.f; rowv[15] = (f16)0.f;
            *(uint4*)&Zx[tid * ZXP]     = *(const uint4*)&rowv[0];
            *(uint4*)&Zx[tid * ZXP + 8] = *(const uint4*)&rowv[8];
        }
        // wait for step t-1 completion of all 64 slices (wave 0 polls)
        if (t > 0 && tid < 64)
            wave_spin(myflg + (size_t)(t - 1) * 64, (unsigned)t, lane, 64);
        __syncthreads();
        // protect ping-pong buffer from in-flight out-head readers (dec);
        // placed BEFORE the gather window so no atomic ops disturb vmcnt.
        if (MODE == 1 && t >= 2) {
            if (tid < 64)
                wave_spin(flg_out + ((size_t)chain * 512 + (t - 2)) * 8,
                          (unsigned)(t - 1), lane, 8);
            __syncthreads();
        }
        ACQ();   // invalidate L1/L2 before cached gather of ping-pong buf

        const f16* hcur = hb0 + (size_t)(t & 1) * (NB * NH);
        const char* ga0 = (const char*)(hcur +
            (size_t)(m0 + (w << 5) + lr) * NH) + (quad << 4);
        const char* ga1 = ga0 + (size_t)16 * NH * 2;   // rt=1 rows (+16)

        f32x4 acc[3][2], accn[2];
#pragma unroll
        for (int g = 0; g < 3; ++g)
#pragma unroll
            for (int rt = 0; rt < 2; ++rt) { f32x4 zv = {0.f,0.f,0.f,0.f}; acc[g][rt] = zv; }
        { f32x4 zv = {0.f,0.f,0.f,0.f}; accn[0] = zv; accn[1] = zv; }

        f16x8 av[8][4];
        // depth-8 chunk pipeline: chunk c = k-tiles 2c,2c+1 (4 loads/chunk).
        AISSUE(0); AISSUE(1); AISSUE(2); AISSUE(3);
        AISSUE(4); AISSUE(5); AISSUE(6); AISSUE(7);
        PW(28); PCONS(0);  AISSUE(8);
        PW(28); PCONS(1);  AISSUE(9);
        PW(28); PCONS(2);  AISSUE(10);
        PW(28); PCONS(3);  AISSUE(11);
        PW(28); PCONS(4);  AISSUE(12);
        PW(28); PCONS(5);  AISSUE(13);
        PW(28); PCONS(6);  AISSUE(14);
        PW(28); PCONS(7);  AISSUE(15);
        PW(28); PCONS(8);
        PW(24); PCONS(9);
        PW(20); PCONS(10);
        PW(16); PCONS(11);
        PW(12); PCONS(12);
        PW(8);  PCONS(13);
        PW(4);  PCONS(14);
        PW(0);  PCONS(15);

        // ext K tiles: xt=0 -> Zx (x,bias); xt>=1 -> z registers (dec)
#pragma unroll
        for (int xt = 0; xt <= NZT; ++xt) {
            const int kt = 32 + xt;
            f16x8 a0, a1;
            if (xt == 0) {
                a0 = *(const f16x8*)(&Zx[((w << 5) + lr) * ZXP + (quad << 3)]);
                a1 = *(const f16x8*)(&Zx[((w << 5) + 16 + lr) * ZXP + (quad << 3)]);
            } else { a0 = azr[0][xt - 1]; a1 = azr[1][xt - 1]; }
#pragma unroll
            for (int g = 0; g < 3; ++g) {
                f16x8 b = *(const f16x8*)(&Wlds[(g * 16 + lr) * KEP + kt * 32 + (quad << 3)]);
                acc[g][0] = MFMA16(a0, b, acc[g][0]);
                acc[g][1] = MFMA16(a1, b, acc[g][1]);
            }
            f16x8 bn = *(const f16x8*)(&wnlds[lr * XKP + xt * 32 + (quad << 3)]);
            accn[0] = MFMA16(a0, bn, accn[0]);
            accn[1] = MFMA16(a1, bn, accn[1]);
        }

        // gate combine + h update (fp32 master in registers); h16 published
        // via packed write-through dword stores (column pairs via shfl_xor)
        f16* hnext = hb0 + (size_t)((t + 1) & 1) * (NB * NH);
#pragma unroll
        for (int rt = 0; rt < 2; ++rt) {
#pragma unroll
            for (int r = 0; r < 4; ++r) {
                const float rr  = acc[0][rt][r];
                const float zz  = acc[1][rt][r];
                const float ghn = acc[2][rt][r];
                const float gin = accn[rt][r];
                const float rg = 1.f / (1.f + __expf(-rr));
                const float zg = 1.f / (1.f + __expf(-zz));
                const float nv = gin + rg * ghn;
                const float e2 = __expf(2.f * nv);
                const float th = 1.f - 2.f / (e2 + 1.f);   // tanh, inf-safe
                const float hn = (1.f - zg) * th + zg * hmast[rt][r];
                hmast[rt][r] = hn;
                const unsigned hv =
                    (unsigned)__builtin_bit_cast(unsigned short, (f16)hn);
                const unsigned ov = (unsigned)__shfl_xor((int)hv, 1, 64);
                if (!(lr & 1)) {
                    const int row = m0 + (w << 5) + rt * 16 + quad * 4 + r;
                    __hip_atomic_store(
                        (unsigned*)&hnext[(size_t)row * NH + j0 + lr],
                        hv | (ov << 16),
                        __ATOMIC_RELAXED, __HIP_MEMORY_SCOPE_AGENT);
                }
            }
        }
        __syncthreads();   // vmcnt(0) drain of all waves' stores before flag
        if (tid == 0)
            __hip_atomic_store(myflg + (size_t)t * 64 + slice, (unsigned)(t + 1),
                               __ATOMIC_RELAXED, __HIP_MEMORY_SCOPE_AGENT);
    }
#undef AISSUE
#undef PCONS

    if (MODE == 0) {
        float* hdst = hf32 + (size_t)dir * NB * NH;
#pragma unroll
        for (int rt = 0; rt < 2; ++rt)
#pragma unroll
            for (int r = 0; r < 4; ++r) {
                const int row = m0 + (w << 5) + rt * 16 + quad * 4 + r;
                hdst[(size_t)row * NH + j0 + lr] = hmast[rt][r];
            }
    }
}

// ---------------------------------------------------------------------------
// heads1: mean / stddev / z from final encoder states (fp32 exact).
// ---------------------------------------------------------------------------
__global__ __launch_bounds__(256) void heads1_kernel(
    const float* __restrict__ hf, const float* __restrict__ hb,
    const float* __restrict__ Wmu, const float* __restrict__ bmu,
    const float* __restrict__ Wvar, const float* __restrict__ bvar,
    const float* __restrict__ noise,
    float* __restrict__ dout, float* __restrict__ z32, f16* __restrict__ z16)
{
    const int tid = threadIdx.x;
    const int b  = ((int)blockIdx.x >> 3) * 16 + (tid >> 4);
    const int zi = ((int)blockIdx.x & 7) * 16 + (tid & 15);
    const float4* h4 = (const float4*)(hf + (size_t)b * NH);
    const float4* g4 = (const float4*)(hb + (size_t)b * NH);
    const float4* m4 = (const float4*)(Wmu + (size_t)zi * (2 * NH));
    const float4* v4 = (const float4*)(Wvar + (size_t)zi * (2 * NH));
    float sm_ = 0.f, sv = 0.f;
    for (int k = 0; k < NH / 4; ++k) {
        const float4 h = h4[k], a = m4[k], c = v4[k];
        sm_ += h.x * a.x + h.y * a.y + h.z * a.z + h.w * a.w;
        sv  += h.x * c.x + h.y * c.y + h.z * c.z + h.w * c.w;
    }
    for (int k = 0; k < NH / 4; ++k) {
        const float4 h = g4[k], a = m4[NH / 4 + k], c = v4[NH / 4 + k];
        sm_ += h.x * a.x + h.y * a.y + h.z * a.z + h.w * a.w;
        sv  += h.x * c.x + h.y * c.y + h.z * c.z + h.w * c.w;
    }
    const float mean = sm_ + bmu[zi];
    const float lv   = sv + bvar[zi];
    const float sd   = __expf(0.5f * lv);
    const float zv   = mean + sd * noise[(size_t)b * NZ + zi];
    dout[OUT_MEAN + (size_t)b * NZ + zi] = mean;
    dout[OUT_STD  + (size_t)b * NZ + zi] = sd;
    z32[b * NZ + zi] = zv;
    z16[b * NZ + zi] = (f16)zv;
}

// ---------------------------------------------------------------------------
// heads2: h_dec0 = tanh(z @ W_init^T + b_init) -> fp32 master + h16 buffer 0.
// ---------------------------------------------------------------------------
__global__ __launch_bounds__(256) void heads2_kernel(
    const float* __restrict__ z32, const float* __restrict__ Winit,
    const float* __restrict__ binit,
    float* __restrict__ h32d, f16* __restrict__ h16d)
{
    __shared__ float Wi[16 * NZ];
    __shared__ float bi[16];
    const int tid = threadIdx.x;
    const int jb = blockIdx.x;
    for (int f = tid; f < 16 * NZ; f += 256)
        Wi[f] = Winit[(size_t)(jb * 16 + (f >> 7)) * NZ + (f & 127)];
    if (tid < 16) bi[tid] = binit[jb * 16 + tid];
    __syncthreads();
    const int b = tid;
    const float4* z4 = (const float4*)(z32 + (size_t)b * NZ);
    float4 zr[NZ / 4];
#pragma unroll
    for (int k = 0; k < NZ / 4; ++k) zr[k] = z4[k];
    for (int hj = 0; hj < 16; ++hj) {
        const float4* w4 = (const float4*)(Wi + hj * NZ);
        float s = bi[hj];
#pragma unroll
        for (int k = 0; k < NZ / 4; ++k) {
            const float4 a = w4[k], z = zr[k];
            s += z.x * a.x + z.y * a.y + z.z * a.z + z.w * a.w;
        }
        const float e2 = __expf(2.f * s);
        const float th = 1.f - 2.f / (e2 + 1.f);
        h32d[(size_t)b * NH + jb * 16 + hj] = th;
        h16d[(size_t)b * NH + jb * 16 + hj] = (f16)th;
    }
}

// ---------------------------------------------------------------------------
extern "C" void kernel_launch(void* const* d_in, const int* in_sizes, int n_in,
                              void* d_out, int out_size, void* d_ws, size_t ws_size,
                              hipStream_t stream)
{
    const float* x     = (const float*)d_in[0];
    const float* noise = (const float*)d_in[1];
    const float* Wihf  = (const float*)d_in[2];
    const float* Whhf  = (const float*)d_in[3];
    const float* bihf  = (const float*)d_in[4];
    const float* bhhf  = (const float*)d_in[5];
    const float* Wihb  = (const float*)d_in[6];
    const float* Whhb  = (const float*)d_in[7];
    const float* bihb  = (const float*)d_in[8];
    const float* bhhb  = (const float*)d_in[9];
    const float* Wmu   = (const float*)d_in[10];
    const float* bmu   = (const float*)d_in[11];
    const float* Wvar  = (const float*)d_in[12];
    const float* bvar  = (const float*)d_in[13];
    const float* Winit = (const float*)d_in[14];
    const float* binit = (const float*)d_in[15];
    const float* Wo    = (const float*)d_in[16];
    const float* bo    = (const float*)d_in[17];
    const float* Wcih  = (const float*)d_in[18];
    const float* Wchh  = (const float*)d_in[19];
    const float* bcih  = (const float*)d_in[20];
    const float* bchh  = (const float*)d_in[21];
    float* dout = (float*)d_out;
    char*  ws   = (char*)d_ws;

    if (ws_size < WS_NEEDED) return;  // ~27.5 MB required

    f16* wmf  = (f16*)(ws + OFF_WMF);
    f16* wmb  = (f16*)(ws + OFF_WMB);
    f16* wmd  = (f16*)(ws + OFF_WMD);
    f16* wnf  = (f16*)(ws + OFF_WNF);
    f16* wnb  = (f16*)(ws + OFF_WNB);
    f16* wnd  = (f16*)(ws + OFF_WND);
    f16* wo16 = (f16*)(ws + OFF_WOUT);
    f16* henc16  = (f16*)(ws + OFF_HENC16);   // [dir][buf][NB*NH]
    float* hf32  = (float*)(ws + OFF_HF32);   // [dir][NB*NH]
    f16* hdec16  = (f16*)(ws + OFF_HDEC16);   // [buf][NB*NH]
    float* h32d  = (float*)(ws + OFF_H32D);
    float* z32p  = (float*)(ws + OFF_Z32);
    f16*   z16p  = (f16*)(ws + OFF_Z16);
    unsigned* flgs  = (unsigned*)(ws + OFF_FLG);
    unsigned* flg_e = flgs;                 // 4*512*64
    unsigned* flg_d = flgs + 131072;        // 2*512*64
    unsigned* flg_o = flgs + 131072 + 65536;// 2*512*8

    prep_kernel<<<2048, 256, 0, stream>>>(
        Whhf, Wihf, bihf, bhhf, Whhb, Wihb, bihb, bhhb,
        Wchh, Wcih, bcih, bchh, Wo, bo,
        wmf, wmb, wmd, wnf, wnb, wnd, wo16,
        henc16 /*dir0 buf0*/, henc16 + (size_t)2 * NB * NH /*dir1 buf0*/,
        flgs);

    // encoder: 512 steps in one persistent launch
    persist_kernel<0><<<256, 256, 0, stream>>>(
        x, wmf, wmb, wnf, wnb, (const f16*)nullptr, (const f16*)nullptr,
        henc16, hf32, (const float*)nullptr, dout, flg_e, (unsigned*)nullptr);

    heads1_kernel<<<128, 256, 0, stream>>>(hf32, hf32 + (size_t)NB * NH,
                                           Wmu, bmu, Wvar, bvar, noise,
                                           dout, z32p, z16p);
    heads2_kernel<<<64, 256, 0, stream>>>(z32p, Winit, binit, h32d, hdec16);

    // decoder: 512 steps + fused sigmoid out-head in one persistent launch
    persist_kernel<1><<<136, 256, 0, stream>>>(
        x, wmd, (const f16*)nullptr, wnd, (const f16*)nullptr, wo16, z16p,
        hdec16, (float*)nullptr, h32d, dout, flg_d, flg_o);
}

// Round 4
// 12772.331 us; speedup vs baseline: 1.2150x; 1.2150x over previous
//
#include <hip/hip_runtime.h>
#include <cstdint>
#include <cstddef>

// ---------------------------------------------------------------------------
// PurifiedVAE persistent-RNN, round 10.
// enc: persist_kernel<0>, 256 WGs = 4 chains (2 dir x 2 batch-halves) x 64 WGs.
// dec: persist_kernel<1>, 128 producer WGs (2 chains x 64) + 8 out-head WGs.
// Weights LDS-resident all 512 steps; fp32 h master in registers.
// r10 = risk-managed r9 retry after an unattributable container failure:
//  ENC (kept from r9): L2-shared h broadcast. Gathers are `sc0` (bypass L1,
//    allocate L2). One WINNER WG per (chain, XCD) -- elected once via an LLC
//    atomic keyed on s_getreg(HW_REG_XCC_ID) -- issues the agent-acquire fence
//    (L2 invalidate) each step after the flag spin, publishes done[chain][xcd];
//    peers wait done >= t. 4 invalidates/XCD/step instead of 32. The XCD L2
//    serves the 64 MB/step broadcast (~8x LLC traffic cut).
//  DEC (reverted to r7 semantics): gathers are `sc0 sc1` (LLC-direct, NO
//    fences, NO election) -- the exact memory protocol that passed in r7.
//    Kept from r9 (protocol-neutral): h quad-buffer (4 slots in the same 4 MB
//    region) and the out-head overwrite guard moved AFTER the gather with 4
//    steps of slack.
// Sync: per-WG one-shot flag slots (value = step+1), wave-parallel polling.
// ---------------------------------------------------------------------------

typedef _Float16 f16;
typedef _Float16 f16x8 __attribute__((ext_vector_type(8)));
typedef float f32x4 __attribute__((ext_vector_type(4)));

#define NB 256
#define NT 512
#define NI 12
#define NH 1024
#define NZ 128
#define NG 3072
#define KE_ENC 1056   // 1024 + 32 ext (x,1,pad)
#define KE_DEC 1184   // 1024 + 160 ext (x,1,pad,z128)
#define XK_ENC 32
#define XK_DEC 160
#define ZXP 40        // Zx row stride in halves (pad: 80 B rows, 2-way banks)

#define MFMA16(a, b, c) __builtin_amdgcn_mfma_f32_16x16x32_f16((a), (b), (c), 0, 0, 0)

// ---- workspace layout (bytes) ----
#define OFF_WMF   ((size_t)0)
#define OFF_WMB   (OFF_WMF + (size_t)NG * KE_ENC * 2)
#define OFF_WMD   (OFF_WMB + (size_t)NG * KE_ENC * 2)
#define OFF_WNF   (OFF_WMD + (size_t)NG * KE_DEC * 2)
#define OFF_WNB   (OFF_WNF + (size_t)NH * XK_ENC * 2)
#define OFF_WND   (OFF_WNB + (size_t)NH * XK_ENC * 2)
#define OFF_WOUT  (OFF_WND + (size_t)NH * XK_DEC * 2)
#define OFF_HENC16 (OFF_WOUT + (size_t)16 * KE_ENC * 2)   // enc [2dir][2buf] / dec [4buf] of [NB*NH] f16
#define OFF_HF32   (OFF_HENC16 + (size_t)4 * NB * NH * 2) // [2 dir][NB*NH] f32
#define OFF_CTL    (OFF_HF32 + (size_t)2 * NB * NH * 4)   // control block (1 MB reserved)
#define OFF_H32D   (OFF_CTL + (size_t)2 * NB * NH * 2)    // [NB*NH] f32
#define OFF_Z32    (OFF_H32D + (size_t)NB * NH * 4)
#define OFF_Z16    (OFF_Z32 + (size_t)NB * NZ * 4)
#define OFF_FLG    (OFF_Z16 + (size_t)NB * NZ * 2)
// flags: enc 4*512*64 | dec 2*512*64 | out 2*512*8  = 204800 u32
#define N_FLG 204800
#define WS_NEEDED (OFF_FLG + (size_t)N_FLG * 4)

// ctl u32 layout (enc only): [0..31] elect_e[4][8] | [32..63] done_e[4][8]
#define N_CTL 1024

// d_out element offsets (fp32): recon [256,512,12], mean [256,128], stddev [256,128]
#define OUT_MEAN (NB * NT * NI)
#define OUT_STD  (OUT_MEAN + NB * NZ)

// whole-wave flag poll: lanes watch nslots (power of 2) slots in parallel.
__device__ __forceinline__ void wave_spin(const unsigned* base, unsigned tgt,
                                          int lane, int nslots) {
    const unsigned* p = base + (lane & (nslots - 1));
    for (;;) {
        unsigned v = __hip_atomic_load(p, __ATOMIC_RELAXED, __HIP_MEMORY_SCOPE_AGENT);
        if (__all((int)(v == tgt))) break;
        __builtin_amdgcn_s_sleep(1);
    }
}

// single-slot monotonic wait (done flags; winner may run ahead -> >=).
__device__ __forceinline__ void done_spin(const unsigned* p, unsigned tgt) {
    for (;;) {
        unsigned v = __hip_atomic_load(p, __ATOMIC_RELAXED, __HIP_MEMORY_SCOPE_AGENT);
        if (v >= tgt) break;
        __builtin_amdgcn_s_sleep(1);
    }
}

// agent-scope acquire: invalidates L1+L2 so cached gathers of the ping-pong
// h buffers cannot observe stale lines (cross-XCD safety). Enc winner-only.
#define ACQ() __builtin_amdgcn_fence(__ATOMIC_ACQUIRE, "agent")

// counted vmcnt wait + scheduling fence. Mask 0x387 = ALU|VALU|SALU|DS may
// cross; MFMA (0x8) and VMEM may NOT -- rule-18 fence keeping register-only
// MFMAs below the waitcnt while letting B-fragment ds_reads prefetch.
#define PW(N) do { \
    asm volatile("s_waitcnt vmcnt(%0)" :: "n"(N) : "memory"); \
    __builtin_amdgcn_sched_barrier(0x387); \
} while (0)

// ---------------------------------------------------------------------------
// prep: build fp16 extended weight matrices, zero initial enc h16 buffers,
// zero flag arrays + control block. (extended-K layout unchanged)
// ---------------------------------------------------------------------------
__global__ __launch_bounds__(256) void prep_kernel(
    const float* __restrict__ Whhf, const float* __restrict__ Wihf,
    const float* __restrict__ bihf, const float* __restrict__ bhhf,
    const float* __restrict__ Whhb, const float* __restrict__ Wihb,
    const float* __restrict__ bihb, const float* __restrict__ bhhb,
    const float* __restrict__ Wchh, const float* __restrict__ Wcih,
    const float* __restrict__ bcih, const float* __restrict__ bchh,
    const float* __restrict__ Wo,   const float* __restrict__ bo,
    f16* __restrict__ wmf, f16* __restrict__ wmb, f16* __restrict__ wmd,
    f16* __restrict__ wnf, f16* __restrict__ wnb, f16* __restrict__ wnd,
    f16* __restrict__ wout,
    f16* __restrict__ h16e0f, f16* __restrict__ h16e0b,
    unsigned* __restrict__ flgs, unsigned* __restrict__ ctl)
{
    const int gsz = gridDim.x * blockDim.x;
    const int gid = blockIdx.x * blockDim.x + threadIdx.x;

    for (int idx = gid; idx < NG * KE_ENC; idx += gsz) {
        const int c = idx / KE_ENC, k = idx - c * KE_ENC;
        float vf, vb;
        if (k < NH) { vf = Whhf[c * NH + k]; vb = Whhb[c * NH + k]; }
        else {
            const int e = k - NH;
            if (c < 2 * NH) {
                if (e < 12)       { vf = Wihf[c * 12 + e]; vb = Wihb[c * 12 + e]; }
                else if (e == 12) { vf = bihf[c] + bhhf[c]; vb = bihb[c] + bhhb[c]; }
                else              { vf = 0.f; vb = 0.f; }
            } else {
                vf = (e == 12) ? bhhf[c] : 0.f;
                vb = (e == 12) ? bhhb[c] : 0.f;
            }
        }
        wmf[idx] = (f16)vf; wmb[idx] = (f16)vb;
    }
    for (int idx = gid; idx < NG * KE_DEC; idx += gsz) {
        const int c = idx / KE_DEC, k = idx - c * KE_DEC;
        float v;
        if (k < NH) v = Wchh[c * NH + k];
        else {
            const int e = k - NH;
            if (c < 2 * NH) {
                if (e < 12)       v = Wcih[c * 140 + e];
                else if (e == 12) v = bcih[c] + bchh[c];
                else if (e < 32)  v = 0.f;
                else              v = Wcih[c * 140 + 12 + (e - 32)];
            } else v = (e == 12) ? bchh[c] : 0.f;
        }
        wmd[idx] = (f16)v;
    }
    for (int idx = gid; idx < NH * XK_ENC; idx += gsz) {
        const int j = idx >> 5, e = idx & 31;
        const int c = 2 * NH + j;
        float vf, vb;
        if (e < 12)       { vf = Wihf[c * 12 + e]; vb = Wihb[c * 12 + e]; }
        else if (e == 12) { vf = bihf[c]; vb = bihb[c]; }
        else              { vf = 0.f; vb = 0.f; }
        wnf[idx] = (f16)vf; wnb[idx] = (f16)vb;
    }
    for (int idx = gid; idx < NH * XK_DEC; idx += gsz) {
        const int j = idx / XK_DEC, e = idx - j * XK_DEC;
        const int c = 2 * NH + j;
        float v;
        if (e < 12)       v = Wcih[c * 140 + e];
        else if (e == 12) v = bcih[c];
        else if (e < 32)  v = 0.f;
        else              v = Wcih[c * 140 + 12 + (e - 32)];
        wnd[idx] = (f16)v;
    }
    for (int idx = gid; idx < 16 * KE_ENC; idx += gsz) {
        const int i = idx / KE_ENC, k = idx - i * KE_ENC;
        float v = 0.f;
        if (i < 12) {
            if (k < NH) v = Wo[i * NH + k];
            else if (k == NH + 12) v = bo[i];
        }
        wout[idx] = (f16)v;
    }
    for (int idx = gid; idx < NB * NH; idx += gsz) {
        h16e0f[idx] = (f16)0.f; h16e0b[idx] = (f16)0.f;
    }
    for (int idx = gid; idx < N_FLG; idx += gsz) flgs[idx] = 0u;
    for (int idx = gid; idx < N_CTL; idx += gsz) ctl[idx] = 0u;
}

// ---------------------------------------------------------------------------
// persist_kernel<MODE>: MODE 0 = encoder (grid 256), MODE 1 = decoder (grid 136).
// Producer WG: chain = bid>>6, slice = bid&63 -> 48 gate-cols {r,z,n} of 16
// h-cols, M=128 batch rows.  Waves M-split 32 rows (2 row-tiles); A fragments
// gathered straight to registers (depth-8 chunk pipeline, no intra-K barriers).
// Out-head WGs (dec, bid>=128): 32 rows x 16 out-cols each, K=1024 wout + ext.
// ---------------------------------------------------------------------------
template<int MODE>
__global__ __launch_bounds__(256, 1) void persist_kernel(
    const float* __restrict__ x,
    const f16* __restrict__ wmF, const f16* __restrict__ wmB_,
    const f16* __restrict__ wnF, const f16* __restrict__ wnB_,
    const f16* __restrict__ wout, const f16* __restrict__ z16,
    f16* __restrict__ hbuf,          // enc: [dir][2][NB*NH]; dec: [4][NB*NH]
    float* __restrict__ hf32,        // enc final fp32 out [dir][NB*NH]
    const float* __restrict__ h32i,  // dec initial master (heads2)
    float* __restrict__ dout,
    unsigned* __restrict__ flg,      // enc [4][512][64] ; dec [2][512][64]
    unsigned* __restrict__ flg_out,  // dec [2][512][8]
    unsigned* __restrict__ ctl)      // enc election + done flags
{
    constexpr int KE  = MODE ? KE_DEC : KE_ENC;
    constexpr int KEP = KE + 8;
    constexpr int XK  = MODE ? XK_DEC : XK_ENC;
    constexpr int XKP = XK + 8;
    constexpr int NZT = MODE ? 4 : 0;   // z-register A k-tiles

    __shared__ f16 Wlds[48 * KEP];      // enc 99.8 KB / dec 111.8 KB
    __shared__ f16 Zx[128 * ZXP];       // 10 KB per-step x+bias A-ext rows
    __shared__ f16 wnlds[16 * XKP];     // gi_n ext weights
    __shared__ int s_win;               // enc: this-WG winner flag

    const int tid = threadIdx.x;
    const int bid = blockIdx.x;
    const int w = tid >> 6, lane = tid & 63;
    const int lr = lane & 15, quad = lane >> 4;

    if (MODE == 1 && bid >= 128) {
        // ---------------- out-head consumer WGs (r7 semantics: sc0 sc1) -----
        const int oc = bid - 128;                 // 0..7
        const int ochain = oc >> 2;
        const int mbase = ochain * 128 + (oc & 3) * 32;
        for (int u = tid; u < 16 * 132; u += 256) {
            const int r = u / 132, kk = u - r * 132;
            *(uint4*)&Wlds[r * 1064 + kk * 8] =
                *(const uint4*)(wout + (size_t)r * KE_ENC + kk * 8);
        }
        __syncthreads();
        if (w >= 2) return;                       // 2 active waves (16 rows each)
        const int rb = mbase + w * 16;
        f16x8 ax;                                 // A-ext: 1.0 at e==12
#pragma unroll
        for (int j = 0; j < 8; ++j) ax[j] = (f16)0.f;
        if (quad == 1) ax[4] = (f16)1.f;

#define OISSUE(c) do { \
    asm volatile( \
        "global_load_dwordx4 %0, %2, off offset:%3 sc0 sc1\n\t" \
        "global_load_dwordx4 %1, %2, off offset:%4 sc0 sc1" \
        : "=&v"(ov[(c) & 7][0]), "=&v"(ov[(c) & 7][1]) \
        : "v"(gao), "n"((c) * 128), "n"((c) * 128 + 64) \
        : "memory"); \
} while (0)
#define OCONS(c) do { \
    _Pragma("unroll") \
    for (int kt2_ = 0; kt2_ < 2; ++kt2_) { \
        const f16x8 b_ = *(const f16x8*)(&Wlds[lr * 1064 + ((c) * 2 + kt2_) * 32 + (quad << 3)]); \
        accq = MFMA16(ov[(c) & 7][kt2_], b_, accq); \
    } \
} while (0)

#pragma unroll 1
        for (int t = 0; t < NT; ++t) {
            wave_spin(flg + ((size_t)ochain * 512 + t) * 64, (unsigned)(t + 1),
                      lane, 64);
            const f16* hc = hbuf + (size_t)((t + 1) & 3) * (NB * NH);
            const char* gao = (const char*)(hc + (size_t)(rb + lr) * NH) + (quad << 4);
            f32x4 accq = {0.f, 0.f, 0.f, 0.f};
            f16x8 ov[8][2];
            OISSUE(0); OISSUE(1); OISSUE(2); OISSUE(3);
            OISSUE(4); OISSUE(5); OISSUE(6); OISSUE(7);
            PW(14); OCONS(0);  OISSUE(8);
            PW(14); OCONS(1);  OISSUE(9);
            PW(14); OCONS(2);  OISSUE(10);
            PW(14); OCONS(3);  OISSUE(11);
            PW(14); OCONS(4);  OISSUE(12);
            PW(14); OCONS(5);  OISSUE(13);
            PW(14); OCONS(6);  OISSUE(14);
            PW(14); OCONS(7);  OISSUE(15);
            PW(14); OCONS(8);
            PW(12); OCONS(9);
            PW(10); OCONS(10);
            PW(8);  OCONS(11);
            PW(6);  OCONS(12);
            PW(4);  OCONS(13);
            PW(2);  OCONS(14);
            PW(0);
            // all hbuf reads have landed in registers: release the buffer slot
            if (lane == 0)
                __hip_atomic_store(
                    &flg_out[((size_t)ochain * 512 + t) * 8 + (oc & 3) * 2 + w],
                    (unsigned)(t + 1), __ATOMIC_RELAXED, __HIP_MEMORY_SCOPE_AGENT);
            OCONS(15);
            {
                const f16x8 b = *(const f16x8*)(&Wlds[lr * 1064 + 1024 + (quad << 3)]);
                accq = MFMA16(ax, b, accq);
            }
            if (lr < NI) {
#pragma unroll
                for (int r = 0; r < 4; ++r) {
                    const int b_ = rb + quad * 4 + r;
                    dout[(size_t)b_ * (NT * NI) + t * NI + lr] =
                        1.f / (1.f + __expf(-accq[r]));
                }
            }
        }
#undef OISSUE
#undef OCONS
        return;
    }

    // ---------------- producer WGs ----------------
    const int chain = bid >> 6;                 // enc 0..3, dec 0..1
    const int slice = bid & 63;
    const int dir = MODE ? 0 : (chain >> 1);
    const int m0 = MODE ? chain * 128 : (chain & 1) * 128;
    const int j0 = slice * 16;

    const f16* wm = (MODE == 0 && dir) ? wmB_ : wmF;
    const f16* wn = (MODE == 0 && dir) ? wnB_ : wnF;
    f16* hb0 = hbuf + (MODE ? (size_t)0 : (size_t)dir * 2 * NB * NH);
    constexpr int BMSK = MODE ? 3 : 1;          // dec quad-buffer, enc ping-pong

    // enc-only: XCD discovery + winner election for the per-XCD L2 fence.
    unsigned* done_slot = nullptr;
    if (MODE == 0) {
        int xcd;
        asm volatile("s_getreg_b32 %0, hwreg(HW_REG_XCC_ID)" : "=s"(xcd));
        xcd &= 7;
        unsigned* elect_slot = ctl + chain * 8 + xcd;
        done_slot = ctl + 32 + chain * 8 + xcd;
        if (tid == 0)
            s_win = (__hip_atomic_fetch_add(elect_slot, 1u, __ATOMIC_RELAXED,
                                            __HIP_MEMORY_SCOPE_AGENT) == 0u);
    }

    // one-time weight load into LDS + Zx zero-init (halves 16..31 stay 0!)
    constexpr int KQ = KE / 8;
    for (int u = tid; u < 48 * KQ; u += 256) {
        const int r = u / KQ, kk = u - r * KQ;
        const int c = (r >> 4) * NH + j0 + (r & 15);
        *(uint4*)&Wlds[r * KEP + kk * 8] = *(const uint4*)(wm + (size_t)c * KE + kk * 8);
    }
    constexpr int XQ = XK / 8;
    for (int u = tid; u < 16 * XQ; u += 256) {
        const int r = u / XQ, kk = u - r * XQ;
        *(uint4*)&wnlds[r * XKP + kk * 8] =
            *(const uint4*)(wn + (size_t)(j0 + r) * XK + kk * 8);
    }
    for (int u = tid; u < 128 * ZXP / 8; u += 256)
        *(uint4*)&Zx[u * 8] = make_uint4(0u, 0u, 0u, 0u);
    __syncthreads();
    const int is_winner = (MODE == 0) ? s_win : 0;

    // register-resident fp32 h master + constant z A-fragments
    float hmast[2][4];
    f16x8 azr[2][NZT ? NZT : 1];
#pragma unroll
    for (int rt = 0; rt < 2; ++rt)
#pragma unroll
        for (int r = 0; r < 4; ++r)
            hmast[rt][r] = MODE
                ? h32i[(size_t)(m0 + (w << 5) + rt * 16 + quad * 4 + r) * NH + j0 + lr]
                : 0.f;
    if (MODE) {
#pragma unroll
        for (int rt = 0; rt < 2; ++rt)
#pragma unroll
            for (int zt = 0; zt < NZT; ++zt)
                azr[rt][zt] = *(const f16x8*)(z16 +
                    (size_t)(m0 + (w << 5) + rt * 16 + lr) * NZ + zt * 32 + (quad << 3));
    }

    unsigned* myflg = flg + (size_t)chain * 512 * 64;

// enc: sc0 (L2-cached, winner-fence coherence); dec: sc0 sc1 (LLC-direct, r7)
#define AISSUE_B(c, BITS) do { \
    asm volatile( \
        "global_load_dwordx4 %0, %4, off offset:%6 " BITS "\n\t" \
        "global_load_dwordx4 %1, %5, off offset:%6 " BITS "\n\t" \
        "global_load_dwordx4 %2, %4, off offset:%7 " BITS "\n\t" \
        "global_load_dwordx4 %3, %5, off offset:%7 " BITS \
        : "=&v"(av[(c) & 7][0]), "=&v"(av[(c) & 7][1]), \
          "=&v"(av[(c) & 7][2]), "=&v"(av[(c) & 7][3]) \
        : "v"(ga0), "v"(ga1), "n"((c) * 128), "n"((c) * 128 + 64) \
        : "memory"); \
} while (0)
#define AISSUE(c) do { \
    if (MODE == 0) AISSUE_B(c, "sc0"); else AISSUE_B(c, "sc0 sc1"); \
} while (0)
#define PCONS(c) do { \
    _Pragma("unroll") \
    for (int kt2_ = 0; kt2_ < 2; ++kt2_) { \
        const f16x8 a0_ = av[(c) & 7][kt2_ * 2]; \
        const f16x8 a1_ = av[(c) & 7][kt2_ * 2 + 1]; \
        _Pragma("unroll") \
        for (int g_ = 0; g_ < 3; ++g_) { \
            const f16x8 b_ = *(const f16x8*)(&Wlds[(g_ * 16 + lr) * KEP + ((c) * 2 + kt2_) * 32 + (quad << 3)]); \
            acc[g_][0] = MFMA16(a0_, b_, acc[g_][0]); \
            acc[g_][1] = MFMA16(a1_, b_, acc[g_][1]); \
        } \
    } \
} while (0)

#pragma unroll 1
    for (int t = 0; t < NT; ++t) {
        // stage per-step A-ext rows (x teacher / x_t, bias 1 at e==12)
        if (tid < 128) {
            f16 rowv[16];
            if (MODE == 1 && t == 0) {
#pragma unroll
                for (int e = 0; e < 12; ++e) rowv[e] = (f16)((e == NI - 1) ? 1.f : 0.f);
            } else {
                const int b_ = m0 + tid;
                const int tx = MODE ? (t - 1) : (dir ? (NT - 1 - t) : t);
                const float4* xr = (const float4*)(x + ((size_t)b_ * NT + tx) * NI);
                const float4 x0 = xr[0], x1 = xr[1], x2 = xr[2];
                rowv[0] = (f16)x0.x; rowv[1] = (f16)x0.y; rowv[2] = (f16)x0.z; rowv[3] = (f16)x0.w;
                rowv[4] = (f16)x1.x; rowv[5] = (f16)x1.y; rowv[6] = (f16)x1.z; rowv[7] = (f16)x1.w;
                rowv[8] = (f16)x2.x; rowv[9] = (f16)x2.y; rowv[10] = (f16)x2.z; rowv[11] = (f16)x2.w;
            }
            rowv[12] = (f16)1.f; rowv[13] = (f16)0.f; rowv[14] = (f16)0.f; rowv[15] = (f16)0.f;
            *(uint4*)&Zx[tid * ZXP]     = *(const uint4*)&rowv[0];
            *(uint4*)&Zx[tid * ZXP + 8] = *(const uint4*)&rowv[8];
        }
        // wait for step t-1 completion of all 64 slices (wave 0 polls).
        // enc: winner then fences the XCD L2 + publishes done; peers wait done.
        if (t > 0 && tid < 64) {
            wave_spin(myflg + (size_t)(t - 1) * 64, (unsigned)t, lane, 64);
            if (MODE == 0) {
                if (is_winner) {
                    ACQ();
                    if (lane == 0)
                        __hip_atomic_store(done_slot, (unsigned)t,
                                           __ATOMIC_RELAXED, __HIP_MEMORY_SCOPE_AGENT);
                } else {
                    done_spin(done_slot, (unsigned)t);
                }
            }
        }
        __syncthreads();

        const f16* hcur = hb0 + (size_t)(t & BMSK) * (NB * NH);
        const char* ga0 = (const char*)(hcur +
            (size_t)(m0 + (w << 5) + lr) * NH) + (quad << 4);
        const char* ga1 = ga0 + (size_t)16 * NH * 2;   // rt=1 rows (+16)

        f32x4 acc[3][2], accn[2];
#pragma unroll
        for (int g = 0; g < 3; ++g)
#pragma unroll
            for (int rt = 0; rt < 2; ++rt) { f32x4 zv = {0.f,0.f,0.f,0.f}; acc[g][rt] = zv; }
        { f32x4 zv = {0.f,0.f,0.f,0.f}; accn[0] = zv; accn[1] = zv; }

        f16x8 av[8][4];
        // depth-8 chunk pipeline: chunk c = k-tiles 2c,2c+1 (4 loads/chunk).
        AISSUE(0); AISSUE(1); AISSUE(2); AISSUE(3);
        AISSUE(4); AISSUE(5); AISSUE(6); AISSUE(7);
        PW(28); PCONS(0);  AISSUE(8);
        PW(28); PCONS(1);  AISSUE(9);
        PW(28); PCONS(2);  AISSUE(10);
        PW(28); PCONS(3);  AISSUE(11);
        PW(28); PCONS(4);  AISSUE(12);
        PW(28); PCONS(5);  AISSUE(13);
        PW(28); PCONS(6);  AISSUE(14);
        PW(28); PCONS(7);  AISSUE(15);
        PW(28); PCONS(8);
        PW(24); PCONS(9);
        PW(20); PCONS(10);
        PW(16); PCONS(11);
        PW(12); PCONS(12);
        PW(8);  PCONS(13);
        PW(4);  PCONS(14);
        PW(0);  PCONS(15);

        // ext K tiles: xt=0 -> Zx (x,bias); xt>=1 -> z registers (dec)
#pragma unroll
        for (int xt = 0; xt <= NZT; ++xt) {
            const int kt = 32 + xt;
            f16x8 a0, a1;
            if (xt == 0) {
                a0 = *(const f16x8*)(&Zx[((w << 5) + lr) * ZXP + (quad << 3)]);
                a1 = *(const f16x8*)(&Zx[((w << 5) + 16 + lr) * ZXP + (quad << 3)]);
            } else { a0 = azr[0][xt - 1]; a1 = azr[1][xt - 1]; }
#pragma unroll
            for (int g = 0; g < 3; ++g) {
                f16x8 b = *(const f16x8*)(&Wlds[(g * 16 + lr) * KEP + kt * 32 + (quad << 3)]);
                acc[g][0] = MFMA16(a0, b, acc[g][0]);
                acc[g][1] = MFMA16(a1, b, acc[g][1]);
            }
            f16x8 bn = *(const f16x8*)(&wnlds[lr * XKP + xt * 32 + (quad << 3)]);
            accn[0] = MFMA16(a0, bn, accn[0]);
            accn[1] = MFMA16(a1, bn, accn[1]);
        }

        // guard the slot we are about to overwrite ((t+1)&3, read by out-head
        // t-4) -- quad-buffer slack means this almost never blocks. Placed
        // after the gather (vmcnt drained) and before the stores it protects.
        if (MODE == 1 && t >= 4) {
            if (tid < 64)
                wave_spin(flg_out + ((size_t)chain * 512 + (t - 4)) * 8,
                          (unsigned)(t - 3), lane, 8);
            __syncthreads();
        }

        // gate combine + h update (fp32 master in registers); h16 published
        // via packed write-through dword stores (column pairs via shfl_xor)
        f16* hnext = hb0 + (size_t)((t + 1) & BMSK) * (NB * NH);
#pragma unroll
        for (int rt = 0; rt < 2; ++rt) {
#pragma unroll
            for (int r = 0; r < 4; ++r) {
                const float rr  = acc[0][rt][r];
                const float zz  = acc[1][rt][r];
                const float ghn = acc[2][rt][r];
                const float gin = accn[rt][r];
                const float rg = 1.f / (1.f + __expf(-rr));
                const float zg = 1.f / (1.f + __expf(-zz));
                const float nv = gin + rg * ghn;
                const float e2 = __expf(2.f * nv);
                const float th = 1.f - 2.f / (e2 + 1.f);   // tanh, inf-safe
                const float hn = (1.f - zg) * th + zg * hmast[rt][r];
                hmast[rt][r] = hn;
                const unsigned hv =
                    (unsigned)__builtin_bit_cast(unsigned short, (f16)hn);
                const unsigned ov = (unsigned)__shfl_xor((int)hv, 1, 64);
                if (!(lr & 1)) {
                    const int row = m0 + (w << 5) + rt * 16 + quad * 4 + r;
                    __hip_atomic_store(
                        (unsigned*)&hnext[(size_t)row * NH + j0 + lr],
                        hv | (ov << 16),
                        __ATOMIC_RELAXED, __HIP_MEMORY_SCOPE_AGENT);
                }
            }
        }
        __syncthreads();   // vmcnt(0) drain of all waves' stores before flag
        if (tid == 0)
            __hip_atomic_store(myflg + (size_t)t * 64 + slice, (unsigned)(t + 1),
                               __ATOMIC_RELAXED, __HIP_MEMORY_SCOPE_AGENT);
    }
#undef AISSUE
#undef AISSUE_B
#undef PCONS

    if (MODE == 0) {
        float* hdst = hf32 + (size_t)dir * NB * NH;
#pragma unroll
        for (int rt = 0; rt < 2; ++rt)
#pragma unroll
            for (int r = 0; r < 4; ++r) {
                const int row = m0 + (w << 5) + rt * 16 + quad * 4 + r;
                hdst[(size_t)row * NH + j0 + lr] = hmast[rt][r];
            }
    }
}

// ---------------------------------------------------------------------------
// heads1: mean / stddev / z from final encoder states (fp32 exact).
// ---------------------------------------------------------------------------
__global__ __launch_bounds__(256) void heads1_kernel(
    const float* __restrict__ hf, const float* __restrict__ hb,
    const float* __restrict__ Wmu, const float* __restrict__ bmu,
    const float* __restrict__ Wvar, const float* __restrict__ bvar,
    const float* __restrict__ noise,
    float* __restrict__ dout, float* __restrict__ z32, f16* __restrict__ z16)
{
    const int tid = threadIdx.x;
    const int b  = ((int)blockIdx.x >> 3) * 16 + (tid >> 4);
    const int zi = ((int)blockIdx.x & 7) * 16 + (tid & 15);
    const float4* h4 = (const float4*)(hf + (size_t)b * NH);
    const float4* g4 = (const float4*)(hb + (size_t)b * NH);
    const float4* m4 = (const float4*)(Wmu + (size_t)zi * (2 * NH));
    const float4* v4 = (const float4*)(Wvar + (size_t)zi * (2 * NH));
    float sm_ = 0.f, sv = 0.f;
    for (int k = 0; k < NH / 4; ++k) {
        const float4 h = h4[k], a = m4[k], c = v4[k];
        sm_ += h.x * a.x + h.y * a.y + h.z * a.z + h.w * a.w;
        sv  += h.x * c.x + h.y * c.y + h.z * c.z + h.w * c.w;
    }
    for (int k = 0; k < NH / 4; ++k) {
        const float4 h = g4[k], a = m4[NH / 4 + k], c = v4[NH / 4 + k];
        sm_ += h.x * a.x + h.y * a.y + h.z * a.z + h.w * a.w;
        sv  += h.x * c.x + h.y * c.y + h.z * c.z + h.w * c.w;
    }
    const float mean = sm_ + bmu[zi];
    const float lv   = sv + bvar[zi];
    const float sd   = __expf(0.5f * lv);
    const float zv   = mean + sd * noise[(size_t)b * NZ + zi];
    dout[OUT_MEAN + (size_t)b * NZ + zi] = mean;
    dout[OUT_STD  + (size_t)b * NZ + zi] = sd;
    z32[b * NZ + zi] = zv;
    z16[b * NZ + zi] = (f16)zv;
}

// ---------------------------------------------------------------------------
// heads2: h_dec0 = tanh(z @ W_init^T + b_init) -> fp32 master + h16 buffer 0.
// ---------------------------------------------------------------------------
__global__ __launch_bounds__(256) void heads2_kernel(
    const float* __restrict__ z32, const float* __restrict__ Winit,
    const float* __restrict__ binit,
    float* __restrict__ h32d, f16* __restrict__ h16d)
{
    __shared__ float Wi[16 * NZ];
    __shared__ float bi[16];
    const int tid = threadIdx.x;
    const int jb = blockIdx.x;
    for (int f = tid; f < 16 * NZ; f += 256)
        Wi[f] = Winit[(size_t)(jb * 16 + (f >> 7)) * NZ + (f & 127)];
    if (tid < 16) bi[tid] = binit[jb * 16 + tid];
    __syncthreads();
    const int b = tid;
    const float4* z4 = (const float4*)(z32 + (size_t)b * NZ);
    float4 zr[NZ / 4];
#pragma unroll
    for (int k = 0; k < NZ / 4; ++k) zr[k] = z4[k];
    for (int hj = 0; hj < 16; ++hj) {
        const float4* w4 = (const float4*)(Wi + hj * NZ);
        float s = bi[hj];
#pragma unroll
        for (int k = 0; k < NZ / 4; ++k) {
            const float4 a = w4[k], z = zr[k];
            s += z.x * a.x + z.y * a.y + z.z * a.z + z.w * a.w;
        }
        const float e2 = __expf(2.f * s);
        const float th = 1.f - 2.f / (e2 + 1.f);
        h32d[(size_t)b * NH + jb * 16 + hj] = th;
        h16d[(size_t)b * NH + jb * 16 + hj] = (f16)th;
    }
}

// ---------------------------------------------------------------------------
extern "C" void kernel_launch(void* const* d_in, const int* in_sizes, int n_in,
                              void* d_out, int out_size, void* d_ws, size_t ws_size,
                              hipStream_t stream)
{
    const float* x     = (const float*)d_in[0];
    const float* noise = (const float*)d_in[1];
    const float* Wihf  = (const float*)d_in[2];
    const float* Whhf  = (const float*)d_in[3];
    const float* bihf  = (const float*)d_in[4];
    const float* bhhf  = (const float*)d_in[5];
    const float* Wihb  = (const float*)d_in[6];
    const float* Whhb  = (const float*)d_in[7];
    const float* bihb  = (const float*)d_in[8];
    const float* bhhb  = (const float*)d_in[9];
    const float* Wmu   = (const float*)d_in[10];
    const float* bmu   = (const float*)d_in[11];
    const float* Wvar  = (const float*)d_in[12];
    const float* bvar  = (const float*)d_in[13];
    const float* Winit = (const float*)d_in[14];
    const float* binit = (const float*)d_in[15];
    const float* Wo    = (const float*)d_in[16];
    const float* bo    = (const float*)d_in[17];
    const float* Wcih  = (const float*)d_in[18];
    const float* Wchh  = (const float*)d_in[19];
    const float* bcih  = (const float*)d_in[20];
    const float* bchh  = (const float*)d_in[21];
    float* dout = (float*)d_out;
    char*  ws   = (char*)d_ws;

    if (ws_size < WS_NEEDED) return;  // ~27.5 MB required

    f16* wmf  = (f16*)(ws + OFF_WMF);
    f16* wmb  = (f16*)(ws + OFF_WMB);
    f16* wmd  = (f16*)(ws + OFF_WMD);
    f16* wnf  = (f16*)(ws + OFF_WNF);
    f16* wnb  = (f16*)(ws + OFF_WNB);
    f16* wnd  = (f16*)(ws + OFF_WND);
    f16* wo16 = (f16*)(ws + OFF_WOUT);
    f16* h16  = (f16*)(ws + OFF_HENC16);      // enc [dir][buf] / dec [4buf]
    float* hf32  = (float*)(ws + OFF_HF32);   // [dir][NB*NH]
    float* h32d  = (float*)(ws + OFF_H32D);
    float* z32p  = (float*)(ws + OFF_Z32);
    f16*   z16p  = (f16*)(ws + OFF_Z16);
    unsigned* ctl   = (unsigned*)(ws + OFF_CTL);
    unsigned* flgs  = (unsigned*)(ws + OFF_FLG);
    unsigned* flg_e = flgs;                 // 4*512*64
    unsigned* flg_d = flgs + 131072;        // 2*512*64
    unsigned* flg_o = flgs + 131072 + 65536;// 2*512*8

    prep_kernel<<<2048, 256, 0, stream>>>(
        Whhf, Wihf, bihf, bhhf, Whhb, Wihb, bihb, bhhb,
        Wchh, Wcih, bcih, bchh, Wo, bo,
        wmf, wmb, wmd, wnf, wnb, wnd, wo16,
        h16 /*dir0 buf0*/, h16 + (size_t)2 * NB * NH /*dir1 buf0*/,
        flgs, ctl);

    // encoder: 512 steps in one persistent launch
    persist_kernel<0><<<256, 256, 0, stream>>>(
        x, wmf, wmb, wnf, wnb, (const f16*)nullptr, (const f16*)nullptr,
        h16, hf32, (const float*)nullptr, dout, flg_e, (unsigned*)nullptr, ctl);

    heads1_kernel<<<128, 256, 0, stream>>>(hf32, hf32 + (size_t)NB * NH,
                                           Wmu, bmu, Wvar, bvar, noise,
                                           dout, z32p, z16p);
    heads2_kernel<<<64, 256, 0, stream>>>(z32p, Winit, binit, h32d, h16 /*slot 0*/);

    // decoder: 512 steps + fused sigmoid out-head in one persistent launch
    persist_kernel<1><<<136, 256, 0, stream>>>(
        x, wmd, (const f16*)nullptr, wnd, (const f16*)nullptr, wo16, z16p,
        h16, (float*)nullptr, h32d, dout, flg_d, flg_o, ctl);
}

// Round 6
// 11252.065 us; speedup vs baseline: 1.3792x; 1.1351x over previous
//
#include <hip/hip_runtime.h>
#include <cstdint>
#include <cstddef>

// ---------------------------------------------------------------------------
// PurifiedVAE persistent-RNN, round 12.
// enc: persist_kernel<0>, 256 WGs = 4 chains (2 dir x 2 batch-halves) x 64 WGs.
// dec: persist_kernel<1>, 128 producer WGs (2 chains x 64) + 8 out-head WGs.
// Weights LDS-resident all 512 steps; fp32 h master in registers.
// r12 = r11 with VGPR-BUDGETED pipeline depth (r11's depth-15 = 240 live
// load-destination VGPRs -> compiler spilled av[] to scratch; spilling the
// destination of an outstanding inline-asm load = silent corruption, absmax
// 0.246). Depths now: producers 10 chunks (40 loads, 160 live VGPRs -- acc
// and azr live in AGPRs on gfx950's unified file), out-heads 12 chunks (24
// loads, 96 VGPRs). All av slots are distinct compile-time constants.
// Kept from r11: enc r7 gather protocol (sc0 sc1 LLC-direct, no fences --
// r8/r10 proved cached-read schemes lose), ext-K MFMAs hoisted above the
// flag spin (h-independent -> off the critical path), dec h quad-buffer,
// out-head overwrite guard after the gather with 4 steps of slack.
// Sync: per-WG one-shot flag slots (value = step+1), wave-parallel polling.
// ---------------------------------------------------------------------------

typedef _Float16 f16;
typedef _Float16 f16x8 __attribute__((ext_vector_type(8)));
typedef float f32x4 __attribute__((ext_vector_type(4)));

#define NB 256
#define NT 512
#define NI 12
#define NH 1024
#define NZ 128
#define NG 3072
#define KE_ENC 1056   // 1024 + 32 ext (x,1,pad)
#define KE_DEC 1184   // 1024 + 160 ext (x,1,pad,z128)
#define XK_ENC 32
#define XK_DEC 160
#define ZXP 40        // Zx row stride in halves (pad: 80 B rows, 2-way banks)

#define MFMA16(a, b, c) __builtin_amdgcn_mfma_f32_16x16x32_f16((a), (b), (c), 0, 0, 0)

// ---- workspace layout (bytes) ----
#define OFF_WMF   ((size_t)0)
#define OFF_WMB   (OFF_WMF + (size_t)NG * KE_ENC * 2)
#define OFF_WMD   (OFF_WMB + (size_t)NG * KE_ENC * 2)
#define OFF_WNF   (OFF_WMD + (size_t)NG * KE_DEC * 2)
#define OFF_WNB   (OFF_WNF + (size_t)NH * XK_ENC * 2)
#define OFF_WND   (OFF_WNB + (size_t)NH * XK_ENC * 2)
#define OFF_WOUT  (OFF_WND + (size_t)NH * XK_DEC * 2)
#define OFF_HENC16 (OFF_WOUT + (size_t)16 * KE_ENC * 2)   // enc [2dir][2buf] / dec [4buf] of [NB*NH] f16
#define OFF_HF32   (OFF_HENC16 + (size_t)4 * NB * NH * 2) // [2 dir][NB*NH] f32
#define OFF_CTL    (OFF_HF32 + (size_t)2 * NB * NH * 4)   // reserved (1 MB, unused)
#define OFF_H32D   (OFF_CTL + (size_t)2 * NB * NH * 2)    // [NB*NH] f32
#define OFF_Z32    (OFF_H32D + (size_t)NB * NH * 4)
#define OFF_Z16    (OFF_Z32 + (size_t)NB * NZ * 4)
#define OFF_FLG    (OFF_Z16 + (size_t)NB * NZ * 2)
// flags: enc 4*512*64 | dec 2*512*64 | out 2*512*8  = 204800 u32
#define N_FLG 204800
#define WS_NEEDED (OFF_FLG + (size_t)N_FLG * 4)

// d_out element offsets (fp32): recon [256,512,12], mean [256,128], stddev [256,128]
#define OUT_MEAN (NB * NT * NI)
#define OUT_STD  (OUT_MEAN + NB * NZ)

// whole-wave flag poll: lanes watch nslots (power of 2) slots in parallel.
__device__ __forceinline__ void wave_spin(const unsigned* base, unsigned tgt,
                                          int lane, int nslots) {
    const unsigned* p = base + (lane & (nslots - 1));
    for (;;) {
        unsigned v = __hip_atomic_load(p, __ATOMIC_RELAXED, __HIP_MEMORY_SCOPE_AGENT);
        if (__all((int)(v == tgt))) break;
        __builtin_amdgcn_s_sleep(1);
    }
}

// counted vmcnt wait + scheduling fence. Mask 0x387 = ALU|VALU|SALU|DS may
// cross; MFMA (0x8) and VMEM may NOT -- rule-18 fence keeping register-only
// MFMAs below the waitcnt while letting B-fragment ds_reads prefetch.
#define PW(N) do { \
    asm volatile("s_waitcnt vmcnt(%0)" :: "n"(N) : "memory"); \
    __builtin_amdgcn_sched_barrier(0x387); \
} while (0)

// ---------------------------------------------------------------------------
// prep: build fp16 extended weight matrices, zero initial enc h16 buffers,
// zero flag arrays. (extended-K layout unchanged)
// ---------------------------------------------------------------------------
__global__ __launch_bounds__(256) void prep_kernel(
    const float* __restrict__ Whhf, const float* __restrict__ Wihf,
    const float* __restrict__ bihf, const float* __restrict__ bhhf,
    const float* __restrict__ Whhb, const float* __restrict__ Wihb,
    const float* __restrict__ bihb, const float* __restrict__ bhhb,
    const float* __restrict__ Wchh, const float* __restrict__ Wcih,
    const float* __restrict__ bcih, const float* __restrict__ bchh,
    const float* __restrict__ Wo,   const float* __restrict__ bo,
    f16* __restrict__ wmf, f16* __restrict__ wmb, f16* __restrict__ wmd,
    f16* __restrict__ wnf, f16* __restrict__ wnb, f16* __restrict__ wnd,
    f16* __restrict__ wout,
    f16* __restrict__ h16e0f, f16* __restrict__ h16e0b,
    unsigned* __restrict__ flgs)
{
    const int gsz = gridDim.x * blockDim.x;
    const int gid = blockIdx.x * blockDim.x + threadIdx.x;

    for (int idx = gid; idx < NG * KE_ENC; idx += gsz) {
        const int c = idx / KE_ENC, k = idx - c * KE_ENC;
        float vf, vb;
        if (k < NH) { vf = Whhf[c * NH + k]; vb = Whhb[c * NH + k]; }
        else {
            const int e = k - NH;
            if (c < 2 * NH) {
                if (e < 12)       { vf = Wihf[c * 12 + e]; vb = Wihb[c * 12 + e]; }
                else if (e == 12) { vf = bihf[c] + bhhf[c]; vb = bihb[c] + bhhb[c]; }
                else              { vf = 0.f; vb = 0.f; }
            } else {
                vf = (e == 12) ? bhhf[c] : 0.f;
                vb = (e == 12) ? bhhb[c] : 0.f;
            }
        }
        wmf[idx] = (f16)vf; wmb[idx] = (f16)vb;
    }
    for (int idx = gid; idx < NG * KE_DEC; idx += gsz) {
        const int c = idx / KE_DEC, k = idx - c * KE_DEC;
        float v;
        if (k < NH) v = Wchh[c * NH + k];
        else {
            const int e = k - NH;
            if (c < 2 * NH) {
                if (e < 12)       v = Wcih[c * 140 + e];
                else if (e == 12) v = bcih[c] + bchh[c];
                else if (e < 32)  v = 0.f;
                else              v = Wcih[c * 140 + 12 + (e - 32)];
            } else v = (e == 12) ? bchh[c] : 0.f;
        }
        wmd[idx] = (f16)v;
    }
    for (int idx = gid; idx < NH * XK_ENC; idx += gsz) {
        const int j = idx >> 5, e = idx & 31;
        const int c = 2 * NH + j;
        float vf, vb;
        if (e < 12)       { vf = Wihf[c * 12 + e]; vb = Wihb[c * 12 + e]; }
        else if (e == 12) { vf = bihf[c]; vb = bihb[c]; }
        else              { vf = 0.f; vb = 0.f; }
        wnf[idx] = (f16)vf; wnb[idx] = (f16)vb;
    }
    for (int idx = gid; idx < NH * XK_DEC; idx += gsz) {
        const int j = idx / XK_DEC, e = idx - j * XK_DEC;
        const int c = 2 * NH + j;
        float v;
        if (e < 12)       v = Wcih[c * 140 + e];
        else if (e == 12) v = bcih[c];
        else if (e < 32)  v = 0.f;
        else              v = Wcih[c * 140 + 12 + (e - 32)];
        wnd[idx] = (f16)v;
    }
    for (int idx = gid; idx < 16 * KE_ENC; idx += gsz) {
        const int i = idx / KE_ENC, k = idx - i * KE_ENC;
        float v = 0.f;
        if (i < 12) {
            if (k < NH) v = Wo[i * NH + k];
            else if (k == NH + 12) v = bo[i];
        }
        wout[idx] = (f16)v;
    }
    for (int idx = gid; idx < NB * NH; idx += gsz) {
        h16e0f[idx] = (f16)0.f; h16e0b[idx] = (f16)0.f;
    }
    for (int idx = gid; idx < N_FLG; idx += gsz) flgs[idx] = 0u;
}

// ---------------------------------------------------------------------------
// persist_kernel<MODE>: MODE 0 = encoder (grid 256), MODE 1 = decoder (grid 136).
// Producer WG: chain = bid>>6, slice = bid&63 -> 48 gate-cols {r,z,n} of 16
// h-cols, M=128 batch rows.  Waves M-split 32 rows (2 row-tiles); A fragments
// gathered straight to registers (depth-10 chunk pipeline, 40 loads in flight).
// Out-head WGs (dec, bid>=128): 32 rows x 16 out-cols each, K=1024 wout + ext.
// ---------------------------------------------------------------------------
template<int MODE>
__global__ __launch_bounds__(256, 1) void persist_kernel(
    const float* __restrict__ x,
    const f16* __restrict__ wmF, const f16* __restrict__ wmB_,
    const f16* __restrict__ wnF, const f16* __restrict__ wnB_,
    const f16* __restrict__ wout, const f16* __restrict__ z16,
    f16* __restrict__ hbuf,          // enc: [dir][2][NB*NH]; dec: [4][NB*NH]
    float* __restrict__ hf32,        // enc final fp32 out [dir][NB*NH]
    const float* __restrict__ h32i,  // dec initial master (heads2)
    float* __restrict__ dout,
    unsigned* __restrict__ flg,      // enc [4][512][64] ; dec [2][512][64]
    unsigned* __restrict__ flg_out)  // dec [2][512][8]
{
    constexpr int KE  = MODE ? KE_DEC : KE_ENC;
    constexpr int KEP = KE + 8;
    constexpr int XK  = MODE ? XK_DEC : XK_ENC;
    constexpr int XKP = XK + 8;
    constexpr int NZT = MODE ? 4 : 0;   // z-register A k-tiles

    __shared__ f16 Wlds[48 * KEP];      // enc 99.8 KB / dec 111.8 KB
    __shared__ f16 Zx[128 * ZXP];       // 10 KB per-step x+bias A-ext rows
    __shared__ f16 wnlds[16 * XKP];     // gi_n ext weights

    const int tid = threadIdx.x;
    const int bid = blockIdx.x;
    const int w = tid >> 6, lane = tid & 63;
    const int lr = lane & 15, quad = lane >> 4;

    if (MODE == 1 && bid >= 128) {
        // ---------------- out-head consumer WGs ----------------
        const int oc = bid - 128;                 // 0..7
        const int ochain = oc >> 2;
        const int mbase = ochain * 128 + (oc & 3) * 32;
        for (int u = tid; u < 16 * 132; u += 256) {
            const int r = u / 132, kk = u - r * 132;
            *(uint4*)&Wlds[r * 1064 + kk * 8] =
                *(const uint4*)(wout + (size_t)r * KE_ENC + kk * 8);
        }
        __syncthreads();
        if (w >= 2) return;                       // 2 active waves (16 rows each)
        const int rb = mbase + w * 16;
        f16x8 ax;                                 // A-ext: 1.0 at e==12
#pragma unroll
        for (int j = 0; j < 8; ++j) ax[j] = (f16)0.f;
        if (quad == 1) ax[4] = (f16)1.f;

#define OISSUE(c) do { \
    asm volatile( \
        "global_load_dwordx4 %0, %2, off offset:%3 sc0 sc1\n\t" \
        "global_load_dwordx4 %1, %2, off offset:%4 sc0 sc1" \
        : "=&v"(ov[(c) & 15][0]), "=&v"(ov[(c) & 15][1]) \
        : "v"(gao), "n"((c) * 128), "n"((c) * 128 + 64) \
        : "memory"); \
} while (0)
#define OCONS(c) do { \
    _Pragma("unroll") \
    for (int kt2_ = 0; kt2_ < 2; ++kt2_) { \
        const f16x8 b_ = *(const f16x8*)(&Wlds[lr * 1064 + ((c) * 2 + kt2_) * 32 + (quad << 3)]); \
        accq = MFMA16(ov[(c) & 15][kt2_], b_, accq); \
    } \
} while (0)

#pragma unroll 1
        for (int t = 0; t < NT; ++t) {
            wave_spin(flg + ((size_t)ochain * 512 + t) * 64, (unsigned)(t + 1),
                      lane, 64);
            const f16* hc = hbuf + (size_t)((t + 1) & 3) * (NB * NH);
            const char* gao = (const char*)(hc + (size_t)(rb + lr) * NH) + (quad << 4);
            f32x4 accq = {0.f, 0.f, 0.f, 0.f};
            f16x8 ov[16][2];
            // depth-12 pipeline: 24 loads in flight (96 live VGPRs)
            OISSUE(0);  OISSUE(1);  OISSUE(2);  OISSUE(3);
            OISSUE(4);  OISSUE(5);  OISSUE(6);  OISSUE(7);
            OISSUE(8);  OISSUE(9);  OISSUE(10); OISSUE(11);
            PW(22); OCONS(0);  OISSUE(12);
            PW(22); OCONS(1);  OISSUE(13);
            PW(22); OCONS(2);  OISSUE(14);
            PW(22); OCONS(3);  OISSUE(15);
            PW(22); OCONS(4);
            PW(20); OCONS(5);
            PW(18); OCONS(6);
            PW(16); OCONS(7);
            PW(14); OCONS(8);
            PW(12); OCONS(9);
            PW(10); OCONS(10);
            PW(8);  OCONS(11);
            PW(6);  OCONS(12);
            PW(4);  OCONS(13);
            PW(2);  OCONS(14);
            PW(0);
            // all hbuf reads have landed in registers: release the buffer slot
            if (lane == 0)
                __hip_atomic_store(
                    &flg_out[((size_t)ochain * 512 + t) * 8 + (oc & 3) * 2 + w],
                    (unsigned)(t + 1), __ATOMIC_RELAXED, __HIP_MEMORY_SCOPE_AGENT);
            OCONS(15);
            {
                const f16x8 b = *(const f16x8*)(&Wlds[lr * 1064 + 1024 + (quad << 3)]);
                accq = MFMA16(ax, b, accq);
            }
            if (lr < NI) {
#pragma unroll
                for (int r = 0; r < 4; ++r) {
                    const int b_ = rb + quad * 4 + r;
                    dout[(size_t)b_ * (NT * NI) + t * NI + lr] =
                        1.f / (1.f + __expf(-accq[r]));
                }
            }
        }
#undef OISSUE
#undef OCONS
        return;
    }

    // ---------------- producer WGs ----------------
    const int chain = bid >> 6;                 // enc 0..3, dec 0..1
    const int slice = bid & 63;
    const int dir = MODE ? 0 : (chain >> 1);
    const int m0 = MODE ? chain * 128 : (chain & 1) * 128;
    const int j0 = slice * 16;

    const f16* wm = (MODE == 0 && dir) ? wmB_ : wmF;
    const f16* wn = (MODE == 0 && dir) ? wnB_ : wnF;
    f16* hb0 = hbuf + (MODE ? (size_t)0 : (size_t)dir * 2 * NB * NH);
    constexpr int BMSK = MODE ? 3 : 1;          // dec quad-buffer, enc ping-pong

    // one-time weight load into LDS + Zx zero-init (halves 16..31 stay 0!)
    constexpr int KQ = KE / 8;
    for (int u = tid; u < 48 * KQ; u += 256) {
        const int r = u / KQ, kk = u - r * KQ;
        const int c = (r >> 4) * NH + j0 + (r & 15);
        *(uint4*)&Wlds[r * KEP + kk * 8] = *(const uint4*)(wm + (size_t)c * KE + kk * 8);
    }
    constexpr int XQ = XK / 8;
    for (int u = tid; u < 16 * XQ; u += 256) {
        const int r = u / XQ, kk = u - r * XQ;
        *(uint4*)&wnlds[r * XKP + kk * 8] =
            *(const uint4*)(wn + (size_t)(j0 + r) * XK + kk * 8);
    }
    for (int u = tid; u < 128 * ZXP / 8; u += 256)
        *(uint4*)&Zx[u * 8] = make_uint4(0u, 0u, 0u, 0u);
    __syncthreads();

    // register-resident fp32 h master + constant z A-fragments
    float hmast[2][4];
    f16x8 azr[2][NZT ? NZT : 1];
#pragma unroll
    for (int rt = 0; rt < 2; ++rt)
#pragma unroll
        for (int r = 0; r < 4; ++r)
            hmast[rt][r] = MODE
                ? h32i[(size_t)(m0 + (w << 5) + rt * 16 + quad * 4 + r) * NH + j0 + lr]
                : 0.f;
    if (MODE) {
#pragma unroll
        for (int rt = 0; rt < 2; ++rt)
#pragma unroll
            for (int zt = 0; zt < NZT; ++zt)
                azr[rt][zt] = *(const f16x8*)(z16 +
                    (size_t)(m0 + (w << 5) + rt * 16 + lr) * NZ + zt * 32 + (quad << 3));
    }

    unsigned* myflg = flg + (size_t)chain * 512 * 64;

#define AISSUE(c) do { \
    asm volatile( \
        "global_load_dwordx4 %0, %4, off offset:%6 sc0 sc1\n\t" \
        "global_load_dwordx4 %1, %5, off offset:%6 sc0 sc1\n\t" \
        "global_load_dwordx4 %2, %4, off offset:%7 sc0 sc1\n\t" \
        "global_load_dwordx4 %3, %5, off offset:%7 sc0 sc1" \
        : "=&v"(av[(c) & 15][0]), "=&v"(av[(c) & 15][1]), \
          "=&v"(av[(c) & 15][2]), "=&v"(av[(c) & 15][3]) \
        : "v"(ga0), "v"(ga1), "n"((c) * 128), "n"((c) * 128 + 64) \
        : "memory"); \
} while (0)
#define PCONS(c) do { \
    _Pragma("unroll") \
    for (int kt2_ = 0; kt2_ < 2; ++kt2_) { \
        const f16x8 a0_ = av[(c) & 15][kt2_ * 2]; \
        const f16x8 a1_ = av[(c) & 15][kt2_ * 2 + 1]; \
        _Pragma("unroll") \
        for (int g_ = 0; g_ < 3; ++g_) { \
            const f16x8 b_ = *(const f16x8*)(&Wlds[(g_ * 16 + lr) * KEP + ((c) * 2 + kt2_) * 32 + (quad << 3)]); \
            acc[g_][0] = MFMA16(a0_, b_, acc[g_][0]); \
            acc[g_][1] = MFMA16(a1_, b_, acc[g_][1]); \
        } \
    } \
} while (0)

#pragma unroll 1
    for (int t = 0; t < NT; ++t) {
        // stage per-step A-ext rows (x teacher / x_t, bias 1 at e==12)
        if (tid < 128) {
            f16 rowv[16];
            if (MODE == 1 && t == 0) {
#pragma unroll
                for (int e = 0; e < 12; ++e) rowv[e] = (f16)((e == NI - 1) ? 1.f : 0.f);
            } else {
                const int b_ = m0 + tid;
                const int tx = MODE ? (t - 1) : (dir ? (NT - 1 - t) : t);
                const float4* xr = (const float4*)(x + ((size_t)b_ * NT + tx) * NI);
                const float4 x0 = xr[0], x1 = xr[1], x2 = xr[2];
                rowv[0] = (f16)x0.x; rowv[1] = (f16)x0.y; rowv[2] = (f16)x0.z; rowv[3] = (f16)x0.w;
                rowv[4] = (f16)x1.x; rowv[5] = (f16)x1.y; rowv[6] = (f16)x1.z; rowv[7] = (f16)x1.w;
                rowv[8] = (f16)x2.x; rowv[9] = (f16)x2.y; rowv[10] = (f16)x2.z; rowv[11] = (f16)x2.w;
            }
            rowv[12] = (f16)1.f; rowv[13] = (f16)0.f; rowv[14] = (f16)0.f; rowv[15] = (f16)0.f;
            *(uint4*)&Zx[tid * ZXP]     = *(const uint4*)&rowv[0];
            *(uint4*)&Zx[tid * ZXP + 8] = *(const uint4*)&rowv[8];
        }
        __syncthreads();   // Zx(t) visible to all waves

        // ext K tiles FIRST (independent of h_t -> off the critical path):
        // xt=0 -> Zx (x,bias); xt>=1 -> z registers (dec)
        f32x4 acc[3][2], accn[2];
#pragma unroll
        for (int g = 0; g < 3; ++g)
#pragma unroll
            for (int rt = 0; rt < 2; ++rt) { f32x4 zv = {0.f,0.f,0.f,0.f}; acc[g][rt] = zv; }
        { f32x4 zv = {0.f,0.f,0.f,0.f}; accn[0] = zv; accn[1] = zv; }
#pragma unroll
        for (int xt = 0; xt <= NZT; ++xt) {
            const int kt = 32 + xt;
            f16x8 a0, a1;
            if (xt == 0) {
                a0 = *(const f16x8*)(&Zx[((w << 5) + lr) * ZXP + (quad << 3)]);
                a1 = *(const f16x8*)(&Zx[((w << 5) + 16 + lr) * ZXP + (quad << 3)]);
            } else { a0 = azr[0][xt - 1]; a1 = azr[1][xt - 1]; }
#pragma unroll
            for (int g = 0; g < 3; ++g) {
                f16x8 b = *(const f16x8*)(&Wlds[(g * 16 + lr) * KEP + kt * 32 + (quad << 3)]);
                acc[g][0] = MFMA16(a0, b, acc[g][0]);
                acc[g][1] = MFMA16(a1, b, acc[g][1]);
            }
            f16x8 bn = *(const f16x8*)(&wnlds[lr * XKP + xt * 32 + (quad << 3)]);
            accn[0] = MFMA16(a0, bn, accn[0]);
            accn[1] = MFMA16(a1, bn, accn[1]);
        }

        // wait for step t-1 completion of all 64 slices (wave 0 polls)
        if (t > 0 && tid < 64)
            wave_spin(myflg + (size_t)(t - 1) * 64, (unsigned)t, lane, 64);
        __syncthreads();

        const f16* hcur = hb0 + (size_t)(t & BMSK) * (NB * NH);
        const char* ga0 = (const char*)(hcur +
            (size_t)(m0 + (w << 5) + lr) * NH) + (quad << 4);
        const char* ga1 = ga0 + (size_t)16 * NH * 2;   // rt=1 rows (+16)

        f16x8 av[16][4];
        // depth-10 pipeline: 40 loads in flight (160 live VGPRs).
        // chunk c = k-tiles 2c,2c+1 (4 loads/chunk).
        AISSUE(0);  AISSUE(1);  AISSUE(2);  AISSUE(3);
        AISSUE(4);  AISSUE(5);  AISSUE(6);  AISSUE(7);
        AISSUE(8);  AISSUE(9);
        PW(36); PCONS(0);  AISSUE(10);
        PW(36); PCONS(1);  AISSUE(11);
        PW(36); PCONS(2);  AISSUE(12);
        PW(36); PCONS(3);  AISSUE(13);
        PW(36); PCONS(4);  AISSUE(14);
        PW(36); PCONS(5);  AISSUE(15);
        PW(36); PCONS(6);
        PW(32); PCONS(7);
        PW(28); PCONS(8);
        PW(24); PCONS(9);
        PW(20); PCONS(10);
        PW(16); PCONS(11);
        PW(12); PCONS(12);
        PW(8);  PCONS(13);
        PW(4);  PCONS(14);
        PW(0);  PCONS(15);

        // guard the slot we are about to overwrite ((t+1)&3, read by out-head
        // t-4) -- quad-buffer slack means this almost never blocks. Placed
        // after the gather (vmcnt drained) and before the stores it protects.
        if (MODE == 1 && t >= 4) {
            if (tid < 64)
                wave_spin(flg_out + ((size_t)chain * 512 + (t - 4)) * 8,
                          (unsigned)(t - 3), lane, 8);
            __syncthreads();
        }

        // gate combine + h update (fp32 master in registers); h16 published
        // via packed write-through dword stores (column pairs via shfl_xor)
        f16* hnext = hb0 + (size_t)((t + 1) & BMSK) * (NB * NH);
#pragma unroll
        for (int rt = 0; rt < 2; ++rt) {
#pragma unroll
            for (int r = 0; r < 4; ++r) {
                const float rr  = acc[0][rt][r];
                const float zz  = acc[1][rt][r];
                const float ghn = acc[2][rt][r];
                const float gin = accn[rt][r];
                const float rg = 1.f / (1.f + __expf(-rr));
                const float zg = 1.f / (1.f + __expf(-zz));
                const float nv = gin + rg * ghn;
                const float e2 = __expf(2.f * nv);
                const float th = 1.f - 2.f / (e2 + 1.f);   // tanh, inf-safe
                const float hn = (1.f - zg) * th + zg * hmast[rt][r];
                hmast[rt][r] = hn;
                const unsigned hv =
                    (unsigned)__builtin_bit_cast(unsigned short, (f16)hn);
                const unsigned ov = (unsigned)__shfl_xor((int)hv, 1, 64);
                if (!(lr & 1)) {
                    const int row = m0 + (w << 5) + rt * 16 + quad * 4 + r;
                    __hip_atomic_store(
                        (unsigned*)&hnext[(size_t)row * NH + j0 + lr],
                        hv | (ov << 16),
                        __ATOMIC_RELAXED, __HIP_MEMORY_SCOPE_AGENT);
                }
            }
        }
        __syncthreads();   // vmcnt(0) drain of all waves' stores before flag
        if (tid == 0)
            __hip_atomic_store(myflg + (size_t)t * 64 + slice, (unsigned)(t + 1),
                               __ATOMIC_RELAXED, __HIP_MEMORY_SCOPE_AGENT);
    }
#undef AISSUE
#undef PCONS

    if (MODE == 0) {
        float* hdst = hf32 + (size_t)dir * NB * NH;
#pragma unroll
        for (int rt = 0; rt < 2; ++rt)
#pragma unroll
            for (int r = 0; r < 4; ++r) {
                const int row = m0 + (w << 5) + rt * 16 + quad * 4 + r;
                hdst[(size_t)row * NH + j0 + lr] = hmast[rt][r];
            }
    }
}

// ---------------------------------------------------------------------------
// heads1: mean / stddev / z from final encoder states (fp32 exact).
// ---------------------------------------------------------------------------
__global__ __launch_bounds__(256) void heads1_kernel(
    const float* __restrict__ hf, const float* __restrict__ hb,
    const float* __restrict__ Wmu, const float* __restrict__ bmu,
    const float* __restrict__ Wvar, const float* __restrict__ bvar,
    const float* __restrict__ noise,
    float* __restrict__ dout, float* __restrict__ z32, f16* __restrict__ z16)
{
    const int tid = threadIdx.x;
    const int b  = ((int)blockIdx.x >> 3) * 16 + (tid >> 4);
    const int zi = ((int)blockIdx.x & 7) * 16 + (tid & 15);
    const float4* h4 = (const float4*)(hf + (size_t)b * NH);
    const float4* g4 = (const float4*)(hb + (size_t)b * NH);
    const float4* m4 = (const float4*)(Wmu + (size_t)zi * (2 * NH));
    const float4* v4 = (const float4*)(Wvar + (size_t)zi * (2 * NH));
    float sm_ = 0.f, sv = 0.f;
    for (int k = 0; k < NH / 4; ++k) {
        const float4 h = h4[k], a = m4[k], c = v4[k];
        sm_ += h.x * a.x + h.y * a.y + h.z * a.z + h.w * a.w;
        sv  += h.x * c.x + h.y * c.y + h.z * c.z + h.w * c.w;
    }
    for (int k = 0; k < NH / 4; ++k) {
        const float4 h = g4[k], a = m4[NH / 4 + k], c = v4[NH / 4 + k];
        sm_ += h.x * a.x + h.y * a.y + h.z * a.z + h.w * a.w;
        sv  += h.x * c.x + h.y * c.y + h.z * c.z + h.w * c.w;
    }
    const float mean = sm_ + bmu[zi];
    const float lv   = sv + bvar[zi];
    const float sd   = __expf(0.5f * lv);
    const float zv   = mean + sd * noise[(size_t)b * NZ + zi];
    dout[OUT_MEAN + (size_t)b * NZ + zi] = mean;
    dout[OUT_STD  + (size_t)b * NZ + zi] = sd;
    z32[b * NZ + zi] = zv;
    z16[b * NZ + zi] = (f16)zv;
}

// ---------------------------------------------------------------------------
// heads2: h_dec0 = tanh(z @ W_init^T + b_init) -> fp32 master + h16 buffer 0.
// ---------------------------------------------------------------------------
__global__ __launch_bounds__(256) void heads2_kernel(
    const float* __restrict__ z32, const float* __restrict__ Winit,
    const float* __restrict__ binit,
    float* __restrict__ h32d, f16* __restrict__ h16d)
{
    __shared__ float Wi[16 * NZ];
    __shared__ float bi[16];
    const int tid = threadIdx.x;
    const int jb = blockIdx.x;
    for (int f = tid; f < 16 * NZ; f += 256)
        Wi[f] = Winit[(size_t)(jb * 16 + (f >> 7)) * NZ + (f & 127)];
    if (tid < 16) bi[tid] = binit[jb * 16 + tid];
    __syncthreads();
    const int b = tid;
    const float4* z4 = (const float4*)(z32 + (size_t)b * NZ);
    float4 zr[NZ / 4];
#pragma unroll
    for (int k = 0; k < NZ / 4; ++k) zr[k] = z4[k];
    for (int hj = 0; hj < 16; ++hj) {
        const float4* w4 = (const float4*)(Wi + hj * NZ);
        float s = bi[hj];
#pragma unroll
        for (int k = 0; k < NZ / 4; ++k) {
            const float4 a = w4[k], z = zr[k];
            s += z.x * a.x + z.y * a.y + z.z * a.z + z.w * a.w;
        }
        const float e2 = __expf(2.f * s);
        const float th = 1.f - 2.f / (e2 + 1.f);
        h32d[(size_t)b * NH + jb * 16 + hj] = th;
        h16d[(size_t)b * NH + jb * 16 + hj] = (f16)th;
    }
}

// ---------------------------------------------------------------------------
extern "C" void kernel_launch(void* const* d_in, const int* in_sizes, int n_in,
                              void* d_out, int out_size, void* d_ws, size_t ws_size,
                              hipStream_t stream)
{
    const float* x     = (const float*)d_in[0];
    const float* noise = (const float*)d_in[1];
    const float* Wihf  = (const float*)d_in[2];
    const float* Whhf  = (const float*)d_in[3];
    const float* bihf  = (const float*)d_in[4];
    const float* bhhf  = (const float*)d_in[5];
    const float* Wihb  = (const float*)d_in[6];
    const float* Whhb  = (const float*)d_in[7];
    const float* bihb  = (const float*)d_in[8];
    const float* bhhb  = (const float*)d_in[9];
    const float* Wmu   = (const float*)d_in[10];
    const float* bmu   = (const float*)d_in[11];
    const float* Wvar  = (const float*)d_in[12];
    const float* bvar  = (const float*)d_in[13];
    const float* Winit = (const float*)d_in[14];
    const float* binit = (const float*)d_in[15];
    const float* Wo    = (const float*)d_in[16];
    const float* bo    = (const float*)d_in[17];
    const float* Wcih  = (const float*)d_in[18];
    const float* Wchh  = (const float*)d_in[19];
    const float* bcih  = (const float*)d_in[20];
    const float* bchh  = (const float*)d_in[21];
    float* dout = (float*)d_out;
    char*  ws   = (char*)d_ws;

    if (ws_size < WS_NEEDED) return;  // ~27.5 MB required

    f16* wmf  = (f16*)(ws + OFF_WMF);
    f16* wmb  = (f16*)(ws + OFF_WMB);
    f16* wmd  = (f16*)(ws + OFF_WMD);
    f16* wnf  = (f16*)(ws + OFF_WNF);
    f16* wnb  = (f16*)(ws + OFF_WNB);
    f16* wnd  = (f16*)(ws + OFF_WND);
    f16* wo16 = (f16*)(ws + OFF_WOUT);
    f16* h16  = (f16*)(ws + OFF_HENC16);      // enc [dir][buf] / dec [4buf]
    float* hf32  = (float*)(ws + OFF_HF32);   // [dir][NB*NH]
    float* h32d  = (float*)(ws + OFF_H32D);
    float* z32p  = (float*)(ws + OFF_Z32);
    f16*   z16p  = (f16*)(ws + OFF_Z16);
    unsigned* flgs  = (unsigned*)(ws + OFF_FLG);
    unsigned* flg_e = flgs;                 // 4*512*64
    unsigned* flg_d = flgs + 131072;        // 2*512*64
    unsigned* flg_o = flgs + 131072 + 65536;// 2*512*8

    prep_kernel<<<2048, 256, 0, stream>>>(
        Whhf, Wihf, bihf, bhhf, Whhb, Wihb, bihb, bhhb,
        Wchh, Wcih, bcih, bchh, Wo, bo,
        wmf, wmb, wmd, wnf, wnb, wnd, wo16,
        h16 /*dir0 buf0*/, h16 + (size_t)2 * NB * NH /*dir1 buf0*/,
        flgs);

    // encoder: 512 steps in one persistent launch
    persist_kernel<0><<<256, 256, 0, stream>>>(
        x, wmf, wmb, wnf, wnb, (const f16*)nullptr, (const f16*)nullptr,
        h16, hf32, (const float*)nullptr, dout, flg_e, (unsigned*)nullptr);

    heads1_kernel<<<128, 256, 0, stream>>>(hf32, hf32 + (size_t)NB * NH,
                                           Wmu, bmu, Wvar, bvar, noise,
                                           dout, z32p, z16p);
    heads2_kernel<<<64, 256, 0, stream>>>(z32p, Winit, binit, h32d, h16 /*slot 0*/);

    // decoder: 512 steps + fused sigmoid out-head in one persistent launch
    persist_kernel<1><<<136, 256, 0, stream>>>(
        x, wmd, (const f16*)nullptr, wnd, (const f16*)nullptr, wo16, z16p,
        h16, (float*)nullptr, h32d, dout, flg_d, flg_o);
}

// Round 7
// 9094.701 us; speedup vs baseline: 1.7063x; 1.2372x over previous
//
#include <hip/hip_runtime.h>
#include <cstdint>
#include <cstddef>

// ---------------------------------------------------------------------------
// PurifiedVAE persistent-RNN, round 13.
// enc: persist_kernel<0>, 256 WGs = 4 chains (2 dir x 2 batch-halves x 128 rows) x 64.
// dec: persist_kernel<1>, 256 WGs = 4 chains (64 batch rows each) x 64 slices.
// r13 CHANGES:
//  1. DEC RESTRUCTURE (the big one): batch is independent in the recurrence,
//     so dec now uses 4 chains x 64 rows (was 2 x 128) -> 256 producer WGs.
//     Aggregate LLC issue rate doubles (dec was governed by WG count, not
//     per-wave depth -- r12's depth-10 was a null result). Per-WG gather
//     halves to 128 KB/step; per wave 16 rows, full-K pipeline (32 loads in
//     flight = 128 VGPRs, the proven-safe budget).
//  2. OUT-HEADS DELETED: slice-0 WGs fold the 12-col out-projection into
//     their regular gather (reuse av chunks; 2 extra MFMAs/chunk vs LDS-
//     resident Wout; recon[t-1] from gathered h_t; epilogue gather of h_512
//     for recon[511]). flg_out interlock + quad-buffer guard gone.
//  3. ext-K hoist REVERTED (r7 order: gather, then ext) -- r12 absmax 0.0195
//     vs 0.0078 was the hoist's accumulation-order change, for zero speed.
//  4. dec flags moved into the formerly-reserved CTL region (WS unchanged).
// Sync: per-WG one-shot flag slots (value = step+1), wave-parallel polling.
// Gather protocol: sc0 sc1 LLC-direct (r8/r10 proved cached schemes lose).
// ---------------------------------------------------------------------------

typedef _Float16 f16;
typedef _Float16 f16x8 __attribute__((ext_vector_type(8)));
typedef float f32x4 __attribute__((ext_vector_type(4)));

#define NB 256
#define NT 512
#define NI 12
#define NH 1024
#define NZ 128
#define NG 3072
#define KE_ENC 1056   // 1024 + 32 ext (x,1,pad)
#define KE_DEC 1184   // 1024 + 160 ext (x,1,pad,z128)
#define XK_ENC 32
#define XK_DEC 160
#define ZXP 40        // Zx row stride in halves (pad: 80 B rows, 2-way banks)

#define MFMA16(a, b, c) __builtin_amdgcn_mfma_f32_16x16x32_f16((a), (b), (c), 0, 0, 0)

// ---- workspace layout (bytes) ----
#define OFF_WMF   ((size_t)0)
#define OFF_WMB   (OFF_WMF + (size_t)NG * KE_ENC * 2)
#define OFF_WMD   (OFF_WMB + (size_t)NG * KE_ENC * 2)
#define OFF_WNF   (OFF_WMD + (size_t)NG * KE_DEC * 2)
#define OFF_WNB   (OFF_WNF + (size_t)NH * XK_ENC * 2)
#define OFF_WND   (OFF_WNB + (size_t)NH * XK_ENC * 2)
#define OFF_WOUT  (OFF_WND + (size_t)NH * XK_DEC * 2)
#define OFF_HENC16 (OFF_WOUT + (size_t)16 * KE_ENC * 2)   // enc [2dir][2buf] / dec [4buf] of [NB*NH] f16
#define OFF_HF32   (OFF_HENC16 + (size_t)4 * NB * NH * 2) // [2 dir][NB*NH] f32
#define OFF_CTL    (OFF_HF32 + (size_t)2 * NB * NH * 4)   // dec flags (1 MB region)
#define OFF_H32D   (OFF_CTL + (size_t)2 * NB * NH * 2)    // [NB*NH] f32
#define OFF_Z32    (OFF_H32D + (size_t)NB * NH * 4)
#define OFF_Z16    (OFF_Z32 + (size_t)NB * NZ * 4)
#define OFF_FLG    (OFF_Z16 + (size_t)NB * NZ * 2)
#define N_FLG 204800          // legacy size, fully zeroed; enc uses first 131072
#define N_FLGD 131072         // dec flags in CTL region: 4*512*64
#define WS_NEEDED (OFF_FLG + (size_t)N_FLG * 4)

// d_out element offsets (fp32): recon [256,512,12], mean [256,128], stddev [256,128]
#define OUT_MEAN (NB * NT * NI)
#define OUT_STD  (OUT_MEAN + NB * NZ)

// whole-wave flag poll: lanes watch nslots (power of 2) slots in parallel.
__device__ __forceinline__ void wave_spin(const unsigned* base, unsigned tgt,
                                          int lane, int nslots) {
    const unsigned* p = base + (lane & (nslots - 1));
    for (;;) {
        unsigned v = __hip_atomic_load(p, __ATOMIC_RELAXED, __HIP_MEMORY_SCOPE_AGENT);
        if (__all((int)(v == tgt))) break;
        __builtin_amdgcn_s_sleep(1);
    }
}

// counted vmcnt wait + scheduling fence (rule-18: MFMA may not hoist above).
#define PW(N) do { \
    asm volatile("s_waitcnt vmcnt(%0)" :: "n"(N) : "memory"); \
    __builtin_amdgcn_sched_barrier(0x387); \
} while (0)

// ---------------------------------------------------------------------------
// prep: build fp16 extended weight matrices, zero initial enc h16 buffers,
// zero flag arrays. (extended-K layout unchanged)
// ---------------------------------------------------------------------------
__global__ __launch_bounds__(256) void prep_kernel(
    const float* __restrict__ Whhf, const float* __restrict__ Wihf,
    const float* __restrict__ bihf, const float* __restrict__ bhhf,
    const float* __restrict__ Whhb, const float* __restrict__ Wihb,
    const float* __restrict__ bihb, const float* __restrict__ bhhb,
    const float* __restrict__ Wchh, const float* __restrict__ Wcih,
    const float* __restrict__ bcih, const float* __restrict__ bchh,
    const float* __restrict__ Wo,   const float* __restrict__ bo,
    f16* __restrict__ wmf, f16* __restrict__ wmb, f16* __restrict__ wmd,
    f16* __restrict__ wnf, f16* __restrict__ wnb, f16* __restrict__ wnd,
    f16* __restrict__ wout,
    f16* __restrict__ h16e0f, f16* __restrict__ h16e0b,
    unsigned* __restrict__ flgs, unsigned* __restrict__ flgd)
{
    const int gsz = gridDim.x * blockDim.x;
    const int gid = blockIdx.x * blockDim.x + threadIdx.x;

    for (int idx = gid; idx < NG * KE_ENC; idx += gsz) {
        const int c = idx / KE_ENC, k = idx - c * KE_ENC;
        float vf, vb;
        if (k < NH) { vf = Whhf[c * NH + k]; vb = Whhb[c * NH + k]; }
        else {
            const int e = k - NH;
            if (c < 2 * NH) {
                if (e < 12)       { vf = Wihf[c * 12 + e]; vb = Wihb[c * 12 + e]; }
                else if (e == 12) { vf = bihf[c] + bhhf[c]; vb = bihb[c] + bhhb[c]; }
                else              { vf = 0.f; vb = 0.f; }
            } else {
                vf = (e == 12) ? bhhf[c] : 0.f;
                vb = (e == 12) ? bhhb[c] : 0.f;
            }
        }
        wmf[idx] = (f16)vf; wmb[idx] = (f16)vb;
    }
    for (int idx = gid; idx < NG * KE_DEC; idx += gsz) {
        const int c = idx / KE_DEC, k = idx - c * KE_DEC;
        float v;
        if (k < NH) v = Wchh[c * NH + k];
        else {
            const int e = k - NH;
            if (c < 2 * NH) {
                if (e < 12)       v = Wcih[c * 140 + e];
                else if (e == 12) v = bcih[c] + bchh[c];
                else if (e < 32)  v = 0.f;
                else              v = Wcih[c * 140 + 12 + (e - 32)];
            } else v = (e == 12) ? bchh[c] : 0.f;
        }
        wmd[idx] = (f16)v;
    }
    for (int idx = gid; idx < NH * XK_ENC; idx += gsz) {
        const int j = idx >> 5, e = idx & 31;
        const int c = 2 * NH + j;
        float vf, vb;
        if (e < 12)       { vf = Wihf[c * 12 + e]; vb = Wihb[c * 12 + e]; }
        else if (e == 12) { vf = bihf[c]; vb = bihb[c]; }
        else              { vf = 0.f; vb = 0.f; }
        wnf[idx] = (f16)vf; wnb[idx] = (f16)vb;
    }
    for (int idx = gid; idx < NH * XK_DEC; idx += gsz) {
        const int j = idx / XK_DEC, e = idx - j * XK_DEC;
        const int c = 2 * NH + j;
        float v;
        if (e < 12)       v = Wcih[c * 140 + e];
        else if (e == 12) v = bcih[c];
        else if (e < 32)  v = 0.f;
        else              v = Wcih[c * 140 + 12 + (e - 32)];
        wnd[idx] = (f16)v;
    }
    for (int idx = gid; idx < 16 * KE_ENC; idx += gsz) {
        const int i = idx / KE_ENC, k = idx - i * KE_ENC;
        float v = 0.f;
        if (i < 12) {
            if (k < NH) v = Wo[i * NH + k];
            else if (k == NH + 12) v = bo[i];
        }
        wout[idx] = (f16)v;
    }
    for (int idx = gid; idx < NB * NH; idx += gsz) {
        h16e0f[idx] = (f16)0.f; h16e0b[idx] = (f16)0.f;
    }
    for (int idx = gid; idx < N_FLG; idx += gsz) flgs[idx] = 0u;
    for (int idx = gid; idx < N_FLGD; idx += gsz) flgd[idx] = 0u;
}

// ---------------------------------------------------------------------------
// persist_kernel<MODE>: grid 256 both. chain = bid>>6, slice = bid&63.
// enc: chain = dir*2 + bhalf, panel 128 rows; wave = 32 rows (2 tiles).
// dec: chain = batch quarter, panel 64 rows; wave = 16 rows (1 tile);
//      slice-0 WGs additionally compute the fused sigmoid out-head from the
//      same av gather (recon[t-1] at step t; epilogue for recon[511]).
// ---------------------------------------------------------------------------
template<int MODE>
__global__ __launch_bounds__(256, 1) void persist_kernel(
    const float* __restrict__ x,
    const f16* __restrict__ wmF, const f16* __restrict__ wmB_,
    const f16* __restrict__ wnF, const f16* __restrict__ wnB_,
    const f16* __restrict__ wout, const f16* __restrict__ z16,
    f16* __restrict__ hbuf,          // enc: [dir][2][NB*NH]; dec: [4][NB*NH]
    float* __restrict__ hf32,        // enc final fp32 out [dir][NB*NH]
    const float* __restrict__ h32i,  // dec initial master (heads2)
    float* __restrict__ dout,
    unsigned* __restrict__ flg)      // [4][512][64]
{
    constexpr int KE  = MODE ? KE_DEC : KE_ENC;
    constexpr int KEP = KE + 8;
    constexpr int XK  = MODE ? XK_DEC : XK_ENC;
    constexpr int XKP = XK + 8;
    constexpr int NZT = MODE ? 4 : 0;   // z-register A k-tiles
    constexpr int NRT = MODE ? 1 : 2;   // row-tiles per wave
    constexpr int MROWS = MODE ? 64 : 128;  // panel rows per chain

    __shared__ f16 Wlds[48 * KEP];          // enc 99.8 KB / dec 111.8 KB
    __shared__ f16 Zx[MROWS * ZXP];         // per-step x+bias A-ext rows
    __shared__ f16 wnlds[16 * XKP];         // gi_n ext weights
    __shared__ f16 wolds[MODE ? 16 * 1064 : 8];  // dec: Wout (slice-0 only)

    const int tid = threadIdx.x;
    const int bid = blockIdx.x;
    const int w = tid >> 6, lane = tid & 63;
    const int lr = lane & 15, quad = lane >> 4;

    const int chain = bid >> 6;                 // 0..3 both modes
    const int slice = bid & 63;
    const int dir = MODE ? 0 : (chain >> 1);
    const int m0 = MODE ? chain * 64 : (chain & 1) * 128;
    const int j0 = slice * 16;
    const bool outw = (MODE == 1) && (slice == 0);  // fused out-head WGs
    const int RB = m0 + (MODE ? (w << 4) : (w << 5));  // wave row base

    const f16* wm = (MODE == 0 && dir) ? wmB_ : wmF;
    const f16* wn = (MODE == 0 && dir) ? wnB_ : wnF;
    f16* hb0 = hbuf + (MODE ? (size_t)0 : (size_t)dir * 2 * NB * NH);
    constexpr int BMSK = MODE ? 3 : 1;

    // one-time weight load into LDS + Zx zero-init (halves 16..31 stay 0!)
    constexpr int KQ = KE / 8;
    for (int u = tid; u < 48 * KQ; u += 256) {
        const int r = u / KQ, kk = u - r * KQ;
        const int c = (r >> 4) * NH + j0 + (r & 15);
        *(uint4*)&Wlds[r * KEP + kk * 8] = *(const uint4*)(wm + (size_t)c * KE + kk * 8);
    }
    constexpr int XQ = XK / 8;
    for (int u = tid; u < 16 * XQ; u += 256) {
        const int r = u / XQ, kk = u - r * XQ;
        *(uint4*)&wnlds[r * XKP + kk * 8] =
            *(const uint4*)(wn + (size_t)(j0 + r) * XK + kk * 8);
    }
    if (outw) {   // WG-uniform branch; barrier below reached by all waves
        for (int u = tid; u < 16 * 132; u += 256) {
            const int r = u / 132, kk = u - r * 132;
            *(uint4*)&wolds[r * 1064 + kk * 8] =
                *(const uint4*)(wout + (size_t)r * KE_ENC + kk * 8);
        }
    }
    for (int u = tid; u < MROWS * ZXP / 8; u += 256)
        *(uint4*)&Zx[u * 8] = make_uint4(0u, 0u, 0u, 0u);
    __syncthreads();

    // register-resident fp32 h master + constant z A-fragments
    float hmast[2][4];
    f16x8 azr[2][NZT ? NZT : 1];
#pragma unroll
    for (int rt = 0; rt < NRT; ++rt)
#pragma unroll
        for (int r = 0; r < 4; ++r)
            hmast[rt][r] = MODE
                ? h32i[(size_t)(RB + rt * 16 + quad * 4 + r) * NH + j0 + lr]
                : 0.f;
    if (MODE) {
#pragma unroll
        for (int rt = 0; rt < NRT; ++rt)
#pragma unroll
            for (int zt = 0; zt < NZT; ++zt)
                azr[rt][zt] = *(const f16x8*)(z16 +
                    (size_t)(RB + rt * 16 + lr) * NZ + zt * 32 + (quad << 3));
    }
    f16x8 ax;   // out-head A-ext: 1.0 at e==12 (quad 1, elem 4)
#pragma unroll
    for (int j = 0; j < 8; ++j) ax[j] = (f16)0.f;
    if (quad == 1) ax[4] = (f16)1.f;

    unsigned* myflg = flg + (size_t)chain * 512 * 64;

// enc: 4 loads/chunk (2 row-tiles); depth-10 ring over 16 distinct slots
#define AISSUE_E(c) do { \
    asm volatile( \
        "global_load_dwordx4 %0, %4, off offset:%6 sc0 sc1\n\t" \
        "global_load_dwordx4 %1, %5, off offset:%6 sc0 sc1\n\t" \
        "global_load_dwordx4 %2, %4, off offset:%7 sc0 sc1\n\t" \
        "global_load_dwordx4 %3, %5, off offset:%7 sc0 sc1" \
        : "=&v"(av[(c) & 15][0]), "=&v"(av[(c) & 15][1]), \
          "=&v"(av[(c) & 15][2]), "=&v"(av[(c) & 15][3]) \
        : "v"(ga0), "v"(ga1), "n"((c) * 128), "n"((c) * 128 + 64) \
        : "memory"); \
} while (0)
#define PCONS_E(c) do { \
    _Pragma("unroll") \
    for (int kt2_ = 0; kt2_ < 2; ++kt2_) { \
        const f16x8 a0_ = av[(c) & 15][kt2_ * 2]; \
        const f16x8 a1_ = av[(c) & 15][kt2_ * 2 + 1]; \
        _Pragma("unroll") \
        for (int g_ = 0; g_ < 3; ++g_) { \
            const f16x8 b_ = *(const f16x8*)(&Wlds[(g_ * 16 + lr) * KEP + ((c) * 2 + kt2_) * 32 + (quad << 3)]); \
            acc[g_][0] = MFMA16(a0_, b_, acc[g_][0]); \
            acc[g_][1] = MFMA16(a1_, b_, acc[g_][1]); \
        } \
    } \
} while (0)
// dec: 2 loads/chunk (1 row-tile); full-K in flight (32 loads, 128 VGPRs)
#define AISSUE_D(c) do { \
    asm volatile( \
        "global_load_dwordx4 %0, %2, off offset:%3 sc0 sc1\n\t" \
        "global_load_dwordx4 %1, %2, off offset:%4 sc0 sc1" \
        : "=&v"(av[(c)][0]), "=&v"(av[(c)][1]) \
        : "v"(ga0), "n"((c) * 128), "n"((c) * 128 + 64) \
        : "memory"); \
} while (0)
#define PCONS_D(c) do { \
    _Pragma("unroll") \
    for (int kt2_ = 0; kt2_ < 2; ++kt2_) { \
        const f16x8 a0_ = av[(c)][kt2_]; \
        _Pragma("unroll") \
        for (int g_ = 0; g_ < 3; ++g_) { \
            const f16x8 b_ = *(const f16x8*)(&Wlds[(g_ * 16 + lr) * KEP + ((c) * 2 + kt2_) * 32 + (quad << 3)]); \
            acc[g_][0] = MFMA16(a0_, b_, acc[g_][0]); \
        } \
        if (outw) { \
            const f16x8 bo_ = *(const f16x8*)(&wolds[lr * 1064 + ((c) * 2 + kt2_) * 32 + (quad << 3)]); \
            accq = MFMA16(a0_, bo_, accq); \
        } \
    } \
} while (0)
#define OCONSQ(c) do { \
    _Pragma("unroll") \
    for (int kt2_ = 0; kt2_ < 2; ++kt2_) { \
        const f16x8 bo_ = *(const f16x8*)(&wolds[lr * 1064 + ((c) * 2 + kt2_) * 32 + (quad << 3)]); \
        accq = MFMA16(av[(c)][kt2_], bo_, accq); \
    } \
} while (0)

#pragma unroll 1
    for (int t = 0; t < NT; ++t) {
        // stage per-step A-ext rows (x teacher / x_t, bias 1 at e==12)
        if (tid < MROWS) {
            f16 rowv[16];
            if (MODE == 1 && t == 0) {
#pragma unroll
                for (int e = 0; e < 12; ++e) rowv[e] = (f16)((e == NI - 1) ? 1.f : 0.f);
            } else {
                const int b_ = m0 + tid;
                const int tx = MODE ? (t - 1) : (dir ? (NT - 1 - t) : t);
                const float4* xr = (const float4*)(x + ((size_t)b_ * NT + tx) * NI);
                const float4 x0 = xr[0], x1 = xr[1], x2 = xr[2];
                rowv[0] = (f16)x0.x; rowv[1] = (f16)x0.y; rowv[2] = (f16)x0.z; rowv[3] = (f16)x0.w;
                rowv[4] = (f16)x1.x; rowv[5] = (f16)x1.y; rowv[6] = (f16)x1.z; rowv[7] = (f16)x1.w;
                rowv[8] = (f16)x2.x; rowv[9] = (f16)x2.y; rowv[10] = (f16)x2.z; rowv[11] = (f16)x2.w;
            }
            rowv[12] = (f16)1.f; rowv[13] = (f16)0.f; rowv[14] = (f16)0.f; rowv[15] = (f16)0.f;
            *(uint4*)&Zx[tid * ZXP]     = *(const uint4*)&rowv[0];
            *(uint4*)&Zx[tid * ZXP + 8] = *(const uint4*)&rowv[8];
        }
        // wait for step t-1 completion of all 64 slices (wave 0 polls)
        if (t > 0 && tid < 64)
            wave_spin(myflg + (size_t)(t - 1) * 64, (unsigned)t, lane, 64);
        __syncthreads();

        const f16* hcur = hb0 + (size_t)(t & BMSK) * (NB * NH);
        const char* ga0 = (const char*)(hcur +
            (size_t)(RB + lr) * NH) + (quad << 4);
        const char* ga1 = ga0 + (size_t)16 * NH * 2;   // enc rt=1 rows
        (void)ga1;

        f32x4 acc[3][2], accn[2];
#pragma unroll
        for (int g = 0; g < 3; ++g)
#pragma unroll
            for (int rt = 0; rt < 2; ++rt) { f32x4 zv = {0.f,0.f,0.f,0.f}; acc[g][rt] = zv; }
        { f32x4 zv = {0.f,0.f,0.f,0.f}; accn[0] = zv; accn[1] = zv; }
        f32x4 accq = {0.f, 0.f, 0.f, 0.f};   // dec slice-0 out accumulator

        if (MODE == 0) {
            f16x8 av[16][4];
            // enc: depth-10 pipeline (40 loads in flight), r12-proven
            AISSUE_E(0);  AISSUE_E(1);  AISSUE_E(2);  AISSUE_E(3);
            AISSUE_E(4);  AISSUE_E(5);  AISSUE_E(6);  AISSUE_E(7);
            AISSUE_E(8);  AISSUE_E(9);
            PW(36); PCONS_E(0);  AISSUE_E(10);
            PW(36); PCONS_E(1);  AISSUE_E(11);
            PW(36); PCONS_E(2);  AISSUE_E(12);
            PW(36); PCONS_E(3);  AISSUE_E(13);
            PW(36); PCONS_E(4);  AISSUE_E(14);
            PW(36); PCONS_E(5);  AISSUE_E(15);
            PW(36); PCONS_E(6);
            PW(32); PCONS_E(7);
            PW(28); PCONS_E(8);
            PW(24); PCONS_E(9);
            PW(20); PCONS_E(10);
            PW(16); PCONS_E(11);
            PW(12); PCONS_E(12);
            PW(8);  PCONS_E(13);
            PW(4);  PCONS_E(14);
            PW(0);  PCONS_E(15);
        } else {
            f16x8 av[16][2];
            // dec: entire K panel in flight (32 loads), counted drain
            AISSUE_D(0);  AISSUE_D(1);  AISSUE_D(2);  AISSUE_D(3);
            AISSUE_D(4);  AISSUE_D(5);  AISSUE_D(6);  AISSUE_D(7);
            AISSUE_D(8);  AISSUE_D(9);  AISSUE_D(10); AISSUE_D(11);
            AISSUE_D(12); AISSUE_D(13); AISSUE_D(14); AISSUE_D(15);
            PW(30); PCONS_D(0);
            PW(28); PCONS_D(1);
            PW(26); PCONS_D(2);
            PW(24); PCONS_D(3);
            PW(22); PCONS_D(4);
            PW(20); PCONS_D(5);
            PW(18); PCONS_D(6);
            PW(16); PCONS_D(7);
            PW(14); PCONS_D(8);
            PW(12); PCONS_D(9);
            PW(10); PCONS_D(10);
            PW(8);  PCONS_D(11);
            PW(6);  PCONS_D(12);
            PW(4);  PCONS_D(13);
            PW(2);  PCONS_D(14);
            PW(0);  PCONS_D(15);
        }

        // ext K tiles (r7 order: after the main gather). xt=0 -> Zx; else z.
#pragma unroll
        for (int xt = 0; xt <= NZT; ++xt) {
            const int kt = 32 + xt;
            f16x8 a0, a1;
            if (xt == 0) {
                a0 = *(const f16x8*)(&Zx[((MODE ? (w << 4) : (w << 5)) + lr) * ZXP + (quad << 3)]);
                if (MODE == 0)
                    a1 = *(const f16x8*)(&Zx[((w << 5) + 16 + lr) * ZXP + (quad << 3)]);
            } else { a0 = azr[0][xt - 1]; if (NRT > 1) a1 = azr[1][xt - 1]; }
#pragma unroll
            for (int g = 0; g < 3; ++g) {
                f16x8 b = *(const f16x8*)(&Wlds[(g * 16 + lr) * KEP + kt * 32 + (quad << 3)]);
                acc[g][0] = MFMA16(a0, b, acc[g][0]);
                if (NRT > 1) acc[g][1] = MFMA16(a1, b, acc[g][1]);
            }
            f16x8 bn = *(const f16x8*)(&wnlds[lr * XKP + xt * 32 + (quad << 3)]);
            accn[0] = MFMA16(a0, bn, accn[0]);
            if (NRT > 1) accn[1] = MFMA16(a1, bn, accn[1]);
        }

        // dec slice-0: finish out = sigmoid(Wout h_t + bo) -> recon[t-1]
        if (outw) {
            const f16x8 bo_ = *(const f16x8*)(&wolds[lr * 1064 + 1024 + (quad << 3)]);
            accq = MFMA16(ax, bo_, accq);
            if (t >= 1 && lr < NI) {
#pragma unroll
                for (int r = 0; r < 4; ++r) {
                    const int b_ = RB + quad * 4 + r;
                    dout[(size_t)b_ * (NT * NI) + (t - 1) * NI + lr] =
                        1.f / (1.f + __expf(-accq[r]));
                }
            }
        }

        // gate combine + h update (fp32 master in registers); h16 published
        // via packed write-through dword stores (column pairs via shfl_xor)
        f16* hnext = hb0 + (size_t)((t + 1) & BMSK) * (NB * NH);
#pragma unroll
        for (int rt = 0; rt < NRT; ++rt) {
#pragma unroll
            for (int r = 0; r < 4; ++r) {
                const float rr  = acc[0][rt][r];
                const float zz  = acc[1][rt][r];
                const float ghn = acc[2][rt][r];
                const float gin = accn[rt][r];
                const float rg = 1.f / (1.f + __expf(-rr));
                const float zg = 1.f / (1.f + __expf(-zz));
                const float nv = gin + rg * ghn;
                const float e2 = __expf(2.f * nv);
                const float th = 1.f - 2.f / (e2 + 1.f);   // tanh, inf-safe
                const float hn = (1.f - zg) * th + zg * hmast[rt][r];
                hmast[rt][r] = hn;
                const unsigned hv =
                    (unsigned)__builtin_bit_cast(unsigned short, (f16)hn);
                const unsigned ov = (unsigned)__shfl_xor((int)hv, 1, 64);
                if (!(lr & 1)) {
                    const int row = RB + rt * 16 + quad * 4 + r;
                    __hip_atomic_store(
                        (unsigned*)&hnext[(size_t)row * NH + j0 + lr],
                        hv | (ov << 16),
                        __ATOMIC_RELAXED, __HIP_MEMORY_SCOPE_AGENT);
                }
            }
        }
        __syncthreads();   // vmcnt(0) drain of all waves' stores before flag
        if (tid == 0)
            __hip_atomic_store(myflg + (size_t)t * 64 + slice, (unsigned)(t + 1),
                               __ATOMIC_RELAXED, __HIP_MEMORY_SCOPE_AGENT);
    }

    if (MODE == 0) {
        float* hdst = hf32 + (size_t)dir * NB * NH;
#pragma unroll
        for (int rt = 0; rt < NRT; ++rt)
#pragma unroll
            for (int r = 0; r < 4; ++r) {
                const int row = RB + rt * 16 + quad * 4 + r;
                hdst[(size_t)row * NH + j0 + lr] = hmast[rt][r];
            }
    }

    // dec slice-0 epilogue: recon[511] = sigmoid(Wout h_512 + bo)
    if (MODE == 1 && outw) {
        if (tid < 64)
            wave_spin(myflg + (size_t)511 * 64, 512u, lane, 64);
        __syncthreads();
        const f16* hc = hb0 + (size_t)(512 & BMSK) * (NB * NH);
        const char* ga0 = (const char*)(hc + (size_t)(RB + lr) * NH) + (quad << 4);
        f32x4 accq = {0.f, 0.f, 0.f, 0.f};
        f16x8 av[16][2];
        AISSUE_D(0);  AISSUE_D(1);  AISSUE_D(2);  AISSUE_D(3);
        AISSUE_D(4);  AISSUE_D(5);  AISSUE_D(6);  AISSUE_D(7);
        AISSUE_D(8);  AISSUE_D(9);  AISSUE_D(10); AISSUE_D(11);
        AISSUE_D(12); AISSUE_D(13); AISSUE_D(14); AISSUE_D(15);
        PW(30); OCONSQ(0);
        PW(28); OCONSQ(1);
        PW(26); OCONSQ(2);
        PW(24); OCONSQ(3);
        PW(22); OCONSQ(4);
        PW(20); OCONSQ(5);
        PW(18); OCONSQ(6);
        PW(16); OCONSQ(7);
        PW(14); OCONSQ(8);
        PW(12); OCONSQ(9);
        PW(10); OCONSQ(10);
        PW(8);  OCONSQ(11);
        PW(6);  OCONSQ(12);
        PW(4);  OCONSQ(13);
        PW(2);  OCONSQ(14);
        PW(0);  OCONSQ(15);
        {
            const f16x8 bo_ = *(const f16x8*)(&wolds[lr * 1064 + 1024 + (quad << 3)]);
            accq = MFMA16(ax, bo_, accq);
        }
        if (lr < NI) {
#pragma unroll
            for (int r = 0; r < 4; ++r) {
                const int b_ = RB + quad * 4 + r;
                dout[(size_t)b_ * (NT * NI) + 511 * NI + lr] =
                    1.f / (1.f + __expf(-accq[r]));
            }
        }
    }
#undef AISSUE_E
#undef PCONS_E
#undef AISSUE_D
#undef PCONS_D
#undef OCONSQ
}

// ---------------------------------------------------------------------------
// heads1: mean / stddev / z from final encoder states (fp32 exact).
// ---------------------------------------------------------------------------
__global__ __launch_bounds__(256) void heads1_kernel(
    const float* __restrict__ hf, const float* __restrict__ hb,
    const float* __restrict__ Wmu, const float* __restrict__ bmu,
    const float* __restrict__ Wvar, const float* __restrict__ bvar,
    const float* __restrict__ noise,
    float* __restrict__ dout, float* __restrict__ z32, f16* __restrict__ z16)
{
    const int tid = threadIdx.x;
    const int b  = ((int)blockIdx.x >> 3) * 16 + (tid >> 4);
    const int zi = ((int)blockIdx.x & 7) * 16 + (tid & 15);
    const float4* h4 = (const float4*)(hf + (size_t)b * NH);
    const float4* g4 = (const float4*)(hb + (size_t)b * NH);
    const float4* m4 = (const float4*)(Wmu + (size_t)zi * (2 * NH));
    const float4* v4 = (const float4*)(Wvar + (size_t)zi * (2 * NH));
    float sm_ = 0.f, sv = 0.f;
    for (int k = 0; k < NH / 4; ++k) {
        const float4 h = h4[k], a = m4[k], c = v4[k];
        sm_ += h.x * a.x + h.y * a.y + h.z * a.z + h.w * a.w;
        sv  += h.x * c.x + h.y * c.y + h.z * c.z + h.w * c.w;
    }
    for (int k = 0; k < NH / 4; ++k) {
        const float4 h = g4[k], a = m4[NH / 4 + k], c = v4[NH / 4 + k];
        sm_ += h.x * a.x + h.y * a.y + h.z * a.z + h.w * a.w;
        sv  += h.x * c.x + h.y * c.y + h.z * c.z + h.w * c.w;
    }
    const float mean = sm_ + bmu[zi];
    const float lv   = sv + bvar[zi];
    const float sd   = __expf(0.5f * lv);
    const float zv   = mean + sd * noise[(size_t)b * NZ + zi];
    dout[OUT_MEAN + (size_t)b * NZ + zi] = mean;
    dout[OUT_STD  + (size_t)b * NZ + zi] = sd;
    z32[b * NZ + zi] = zv;
    z16[b * NZ + zi] = (f16)zv;
}

// ---------------------------------------------------------------------------
// heads2: h_dec0 = tanh(z @ W_init^T + b_init) -> fp32 master + h16 buffer 0.
// ---------------------------------------------------------------------------
__global__ __launch_bounds__(256) void heads2_kernel(
    const float* __restrict__ z32, const float* __restrict__ Winit,
    const float* __restrict__ binit,
    float* __restrict__ h32d, f16* __restrict__ h16d)
{
    __shared__ float Wi[16 * NZ];
    __shared__ float bi[16];
    const int tid = threadIdx.x;
    const int jb = blockIdx.x;
    for (int f = tid; f < 16 * NZ; f += 256)
        Wi[f] = Winit[(size_t)(jb * 16 + (f >> 7)) * NZ + (f & 127)];
    if (tid < 16) bi[tid] = binit[jb * 16 + tid];
    __syncthreads();
    const int b = tid;
    const float4* z4 = (const float4*)(z32 + (size_t)b * NZ);
    float4 zr[NZ / 4];
#pragma unroll
    for (int k = 0; k < NZ / 4; ++k) zr[k] = z4[k];
    for (int hj = 0; hj < 16; ++hj) {
        const float4* w4 = (const float4*)(Wi + hj * NZ);
        float s = bi[hj];
#pragma unroll
        for (int k = 0; k < NZ / 4; ++k) {
            const float4 a = w4[k], z = zr[k];
            s += z.x * a.x + z.y * a.y + z.z * a.z + z.w * a.w;
        }
        const float e2 = __expf(2.f * s);
        const float th = 1.f - 2.f / (e2 + 1.f);
        h32d[(size_t)b * NH + jb * 16 + hj] = th;
        h16d[(size_t)b * NH + jb * 16 + hj] = (f16)th;
    }
}

// ---------------------------------------------------------------------------
extern "C" void kernel_launch(void* const* d_in, const int* in_sizes, int n_in,
                              void* d_out, int out_size, void* d_ws, size_t ws_size,
                              hipStream_t stream)
{
    const float* x     = (const float*)d_in[0];
    const float* noise = (const float*)d_in[1];
    const float* Wihf  = (const float*)d_in[2];
    const float* Whhf  = (const float*)d_in[3];
    const float* bihf  = (const float*)d_in[4];
    const float* bhhf  = (const float*)d_in[5];
    const float* Wihb  = (const float*)d_in[6];
    const float* Whhb  = (const float*)d_in[7];
    const float* bihb  = (const float*)d_in[8];
    const float* bhhb  = (const float*)d_in[9];
    const float* Wmu   = (const float*)d_in[10];
    const float* bmu   = (const float*)d_in[11];
    const float* Wvar  = (const float*)d_in[12];
    const float* bvar  = (const float*)d_in[13];
    const float* Winit = (const float*)d_in[14];
    const float* binit = (const float*)d_in[15];
    const float* Wo    = (const float*)d_in[16];
    const float* bo    = (const float*)d_in[17];
    const float* Wcih  = (const float*)d_in[18];
    const float* Wchh  = (const float*)d_in[19];
    const float* bcih  = (const float*)d_in[20];
    const float* bchh  = (const float*)d_in[21];
    float* dout = (float*)d_out;
    char*  ws   = (char*)d_ws;

    if (ws_size < WS_NEEDED) return;  // ~27.5 MB required

    f16* wmf  = (f16*)(ws + OFF_WMF);
    f16* wmb  = (f16*)(ws + OFF_WMB);
    f16* wmd  = (f16*)(ws + OFF_WMD);
    f16* wnf  = (f16*)(ws + OFF_WNF);
    f16* wnb  = (f16*)(ws + OFF_WNB);
    f16* wnd  = (f16*)(ws + OFF_WND);
    f16* wo16 = (f16*)(ws + OFF_WOUT);
    f16* h16  = (f16*)(ws + OFF_HENC16);      // enc [dir][buf] / dec [4buf]
    float* hf32  = (float*)(ws + OFF_HF32);   // [dir][NB*NH]
    float* h32d  = (float*)(ws + OFF_H32D);
    float* z32p  = (float*)(ws + OFF_Z32);
    f16*   z16p  = (f16*)(ws + OFF_Z16);
    unsigned* flg_e = (unsigned*)(ws + OFF_FLG);   // enc 4*512*64
    unsigned* flg_d = (unsigned*)(ws + OFF_CTL);   // dec 4*512*64

    prep_kernel<<<2048, 256, 0, stream>>>(
        Whhf, Wihf, bihf, bhhf, Whhb, Wihb, bihb, bhhb,
        Wchh, Wcih, bcih, bchh, Wo, bo,
        wmf, wmb, wmd, wnf, wnb, wnd, wo16,
        h16 /*dir0 buf0*/, h16 + (size_t)2 * NB * NH /*dir1 buf0*/,
        flg_e, flg_d);

    // encoder: 512 steps in one persistent launch
    persist_kernel<0><<<256, 256, 0, stream>>>(
        x, wmf, wmb, wnf, wnb, (const f16*)nullptr, (const f16*)nullptr,
        h16, hf32, (const float*)nullptr, dout, flg_e);

    heads1_kernel<<<128, 256, 0, stream>>>(hf32, hf32 + (size_t)NB * NH,
                                           Wmu, bmu, Wvar, bvar, noise,
                                           dout, z32p, z16p);
    heads2_kernel<<<64, 256, 0, stream>>>(z32p, Winit, binit, h32d, h16 /*slot 0*/);

    // decoder: 512 steps, 4 batch-chains x 64 slices, fused out-head
    persist_kernel<1><<<256, 256, 0, stream>>>(
        x, wmd, (const f16*)nullptr, wnd, (const f16*)nullptr, wo16, z16p,
        h16, (float*)nullptr, h32d, dout, flg_d);
}